// Round 1
// baseline (2773.211 us; speedup 1.0000x reference)
//
#include <hip/hip_runtime.h>
#include <math.h>

// Problem dims
constexpr int  Bn   = 512;              // batches
constexpr int  Cch  = 64;               // EEG channels
constexpr int  Dd   = 512;              // feature dim
constexpr int  DV3  = 192;              // 3*DV
constexpr long BCD  = (long)Bn * Cch * Dd;     // per-branch x elements
constexpr int  MTOT = Bn * Cch;                // 32768
constexpr long NZv  = (long)Bn * Cch * DV3;    // 6,291,456

__device__ __forceinline__ float eluf(float v) { return v > 0.f ? v : expm1f(v); }

// ---------------- dynamic graph: A_dyn / A_norm (3 blocks) ----------------
__global__ __launch_bounds__(256) void k_dyngraph(
    const float* __restrict__ A_init,
    const float* __restrict__ f1w, const float* __restrict__ f1b,
    const float* __restrict__ f2w, const float* __restrict__ f2b,
    float* __restrict__ A_dyn, float* __restrict__ A_norm)
{
  int br = blockIdx.x, t = threadIdx.x;
  __shared__ float sA[4096];
  __shared__ float sMid[256];
  __shared__ float sDyn[4096];
  __shared__ float sSum[64];
  for (int i = t; i < 4096; i += 256) sA[i] = A_init[i];
  __syncthreads();
  const float* w1 = f1w + (long)br * 4096 * 256;
  float acc = f1b[br * 256 + t];
  #pragma unroll 8
  for (int k = 0; k < 4096; ++k) acc = fmaf(sA[k], w1[(long)k * 256 + t], acc);
  sMid[t] = eluf(acc);
  __syncthreads();
  const float* w2 = f2w + (long)br * 256 * 4096;
  const float* b2 = f2b + br * 4096;
  for (int j = t; j < 4096; j += 256) {
    float a = b2[j];
    #pragma unroll 8
    for (int k = 0; k < 256; ++k) a = fmaf(sMid[k], w2[(long)k * 4096 + j], a);
    a = fmaxf(a, 0.f);
    sDyn[j] = a;
    A_dyn[br * 4096 + j] = a;
  }
  __syncthreads();
  if (t < 64) {
    float s = 0.f;
    for (int j = 0; j < 64; ++j) s += sDyn[t * 64 + j];
    sSum[t] = s + 1e-6f;
  }
  __syncthreads();
  for (int j = t; j < 4096; j += 256)
    A_norm[br * 4096 + j] = sDyn[j] / sSum[j >> 6];
}

// ---------------- generic f32 GEMM: out = ACT(A@W + bias) [+resid] ----------------
// A: (M,K) lda; W: (K,N) row-major; tiles 64x64x16; block 256; thread 4x4.
// ACT: 0 none, 1 relu, 2 elu. SPLITK: z indexes K-chunk, out += z*o_zs.
template<int ACT, bool RES, bool SPLITK>
__global__ __launch_bounds__(256) void k_gemm(
    int M, int N, int K,
    const float* __restrict__ A, long a_zs, int lda,
    const float* __restrict__ W, long w_zs,
    const float* __restrict__ bias, long b_zs,
    float* __restrict__ out, long o_zs,
    const float* __restrict__ resid, int k_chunk)
{
  int z  = blockIdx.z;
  int n0 = blockIdx.x * 64, m0 = blockIdx.y * 64;
  const float* Ab = A + (SPLITK ? 0 : z * a_zs);
  const float* Wb = W + (SPLITK ? 0 : z * w_zs);
  float* ob = out + z * o_zs;
  const float* bb = bias ? bias + z * b_zs : nullptr;
  const float* rb_ = RES ? resid + z * o_zs : nullptr;
  int k0   = SPLITK ? z * k_chunk : 0;
  int kend = SPLITK ? k0 + k_chunk : K;

  __shared__ float As[16][68];
  __shared__ float Bs[16][68];
  float acc[4][4] = {};
  int t  = threadIdx.x;
  int tm = t & 15, tn = t >> 4;
  int ar = t >> 2, ak = (t & 3) * 4;
  int bk = t >> 4, bn = (t & 15) * 4;

  for (int kt = k0; kt < kend; kt += 16) {
    float4 av = *(const float4*)&Ab[(long)(m0 + ar) * lda + kt + ak];
    float4 bv = *(const float4*)&Wb[(long)(kt + bk) * N + n0 + bn];
    __syncthreads();   // previous iter's compute reads complete
    As[ak + 0][ar] = av.x; As[ak + 1][ar] = av.y;
    As[ak + 2][ar] = av.z; As[ak + 3][ar] = av.w;
    *(float4*)&Bs[bk][bn] = bv;
    __syncthreads();
    #pragma unroll
    for (int k = 0; k < 16; ++k) {
      float4 a = *(const float4*)&As[k][tm * 4];
      float4 b = *(const float4*)&Bs[k][tn * 4];
      acc[0][0] = fmaf(a.x, b.x, acc[0][0]); acc[0][1] = fmaf(a.x, b.y, acc[0][1]);
      acc[0][2] = fmaf(a.x, b.z, acc[0][2]); acc[0][3] = fmaf(a.x, b.w, acc[0][3]);
      acc[1][0] = fmaf(a.y, b.x, acc[1][0]); acc[1][1] = fmaf(a.y, b.y, acc[1][1]);
      acc[1][2] = fmaf(a.y, b.z, acc[1][2]); acc[1][3] = fmaf(a.y, b.w, acc[1][3]);
      acc[2][0] = fmaf(a.z, b.x, acc[2][0]); acc[2][1] = fmaf(a.z, b.y, acc[2][1]);
      acc[2][2] = fmaf(a.z, b.z, acc[2][2]); acc[2][3] = fmaf(a.z, b.w, acc[2][3]);
      acc[3][0] = fmaf(a.w, b.x, acc[3][0]); acc[3][1] = fmaf(a.w, b.y, acc[3][1]);
      acc[3][2] = fmaf(a.w, b.z, acc[3][2]); acc[3][3] = fmaf(a.w, b.w, acc[3][3]);
    }
  }

  #pragma unroll
  for (int i = 0; i < 4; ++i) {
    long row = m0 + tm * 4 + i;
    int  col = n0 + tn * 4;
    float v[4];
    #pragma unroll
    for (int j = 0; j < 4; ++j) {
      float x = acc[i][j] + (bb ? bb[col + j] : 0.f);
      if (ACT == 1) x = fmaxf(x, 0.f);
      if (ACT == 2) x = eluf(x);
      v[j] = x;
    }
    if (RES) {
      float4 r = *(const float4*)&rb_[row * N + col];
      v[0] += r.x; v[1] += r.y; v[2] += r.z; v[3] += r.w;
    }
    float4 o; o.x = v[0]; o.y = v[1]; o.z = v[2]; o.w = v[3];
    *(float4*)&ob[row * N + col] = o;
  }
}

// ---------------- graph diffusion: G = elu(A_norm @ h + x), per (batch,branch) ----------------
__global__ __launch_bounds__(256) void k_diffuse(
    const float* __restrict__ A_norm, const float* __restrict__ h,
    const float* __restrict__ x, float* __restrict__ G, int b0, int NB)
{
  int b = blockIdx.x, br = blockIdx.y, t = threadIdx.x;
  __shared__ float sAT[64 * 64];   // transposed: sAT[j*64+i] = A_norm[i][j]
  __shared__ float sH[64 * 64];    // 64-col chunk of h
  const float* An = A_norm + br * 4096;
  for (int idx = t; idx < 4096; idx += 256)
    sAT[(idx & 63) * 64 + (idx >> 6)] = An[idx];
  const float* hb = h + ((long)br * NB + b) * (64 * 512);
  const float* xb = x + ((long)br * Bn + (b0 + b)) * (64 * 512);
  float* Gb = G + ((long)br * NB + b) * (64 * 512);
  int c4 = t & 15, rb = (t >> 4) * 4;
  for (int dc = 0; dc < 512; dc += 64) {
    __syncthreads();
    for (int idx = t * 4; idx < 4096; idx += 1024) {
      int r = idx >> 6, c = idx & 63;
      *(float4*)&sH[idx] = *(const float4*)&hb[(long)r * 512 + dc + c];
    }
    __syncthreads();
    float acc[4][4] = {};
    #pragma unroll 4
    for (int j = 0; j < 64; ++j) {
      float a0 = sAT[j * 64 + rb + 0], a1 = sAT[j * 64 + rb + 1];
      float a2 = sAT[j * 64 + rb + 2], a3 = sAT[j * 64 + rb + 3];
      float4 hv = *(const float4*)&sH[j * 64 + c4 * 4];
      acc[0][0] = fmaf(a0, hv.x, acc[0][0]); acc[0][1] = fmaf(a0, hv.y, acc[0][1]);
      acc[0][2] = fmaf(a0, hv.z, acc[0][2]); acc[0][3] = fmaf(a0, hv.w, acc[0][3]);
      acc[1][0] = fmaf(a1, hv.x, acc[1][0]); acc[1][1] = fmaf(a1, hv.y, acc[1][1]);
      acc[1][2] = fmaf(a1, hv.z, acc[1][2]); acc[1][3] = fmaf(a1, hv.w, acc[1][3]);
      acc[2][0] = fmaf(a2, hv.x, acc[2][0]); acc[2][1] = fmaf(a2, hv.y, acc[2][1]);
      acc[2][2] = fmaf(a2, hv.z, acc[2][2]); acc[2][3] = fmaf(a2, hv.w, acc[2][3]);
      acc[3][0] = fmaf(a3, hv.x, acc[3][0]); acc[3][1] = fmaf(a3, hv.y, acc[3][1]);
      acc[3][2] = fmaf(a3, hv.z, acc[3][2]); acc[3][3] = fmaf(a3, hv.w, acc[3][3]);
    }
    #pragma unroll
    for (int i = 0; i < 4; ++i) {
      float4 xv = *(const float4*)&xb[(long)(rb + i) * 512 + dc + c4 * 4];
      float4 o;
      o.x = eluf(acc[i][0] + xv.x); o.y = eluf(acc[i][1] + xv.y);
      o.z = eluf(acc[i][2] + xv.z); o.w = eluf(acc[i][3] + xv.w);
      *(float4*)&Gb[(long)(rb + i) * 512 + dc + c4 * 4] = o;
    }
  }
}

// ---------------- attention + A_dyn apply, per (batch,branch) ----------------
__global__ __launch_bounds__(256) void k_attn(
    const float* __restrict__ Q, const float* __restrict__ Km,
    const float* __restrict__ V, const float* __restrict__ A_dyn,
    float* __restrict__ Zl, int b0, int NB)
{
  int b = blockIdx.x, br = blockIdx.y, t = threadIdx.x;
  __shared__ float sQ[64 * 65];
  __shared__ float sK[64 * 65];
  __shared__ float sS[64 * 65];
  long base = ((long)br * NB + b) * (64 * 64);
  const float* Qb = Q + base;
  const float* Kb = Km + base;
  const float* Vb = V + base;
  for (int idx = t * 4; idx < 4096; idx += 1024) {
    int r = idx >> 6, c = idx & 63;
    float4 q4 = *(const float4*)&Qb[idx];
    float4 k4 = *(const float4*)&Kb[idx];
    sQ[r * 65 + c + 0] = q4.x; sQ[r * 65 + c + 1] = q4.y;
    sQ[r * 65 + c + 2] = q4.z; sQ[r * 65 + c + 3] = q4.w;
    sK[r * 65 + c + 0] = k4.x; sK[r * 65 + c + 1] = k4.y;
    sK[r * 65 + c + 2] = k4.z; sK[r * 65 + c + 3] = k4.w;
  }
  __syncthreads();
  int c4 = t & 15, rb = (t >> 4) * 4;
  float acc[4][4] = {};
  #pragma unroll 4
  for (int k = 0; k < 64; ++k) {
    float a0 = sQ[(rb + 0) * 65 + k], a1 = sQ[(rb + 1) * 65 + k];
    float a2 = sQ[(rb + 2) * 65 + k], a3 = sQ[(rb + 3) * 65 + k];
    #pragma unroll
    for (int q = 0; q < 4; ++q) {
      float bq = sK[(c4 * 4 + q) * 65 + k];
      acc[0][q] = fmaf(a0, bq, acc[0][q]); acc[1][q] = fmaf(a1, bq, acc[1][q]);
      acc[2][q] = fmaf(a2, bq, acc[2][q]); acc[3][q] = fmaf(a3, bq, acc[3][q]);
    }
  }
  #pragma unroll
  for (int i = 0; i < 4; ++i)
    #pragma unroll
    for (int q = 0; q < 4; ++q)
      sS[(rb + i) * 65 + c4 * 4 + q] = acc[i][q] * 0.125f;
  __syncthreads();
  {  // row softmax: 4 threads per row (same quad in a wave)
    int r = t >> 2, l = t & 3;
    float m = -3.4e38f;
    #pragma unroll
    for (int c = 0; c < 16; ++c) m = fmaxf(m, sS[r * 65 + l * 16 + c]);
    m = fmaxf(m, __shfl_xor(m, 1));
    m = fmaxf(m, __shfl_xor(m, 2));
    float s = 0.f, e[16];
    #pragma unroll
    for (int c = 0; c < 16; ++c) { e[c] = expf(sS[r * 65 + l * 16 + c] - m); s += e[c]; }
    s += __shfl_xor(s, 1);
    s += __shfl_xor(s, 2);
    float inv = 1.f / s;
    #pragma unroll
    for (int c = 0; c < 16; ++c) sS[r * 65 + l * 16 + c] = e[c] * inv;
  }
  __syncthreads();
  for (int idx = t * 4; idx < 4096; idx += 1024) {  // V -> sQ (Q dead)
    int r = idx >> 6, c = idx & 63;
    float4 v4 = *(const float4*)&Vb[idx];
    sQ[r * 65 + c + 0] = v4.x; sQ[r * 65 + c + 1] = v4.y;
    sQ[r * 65 + c + 2] = v4.z; sQ[r * 65 + c + 3] = v4.w;
  }
  __syncthreads();
  float pv[4][4] = {};
  #pragma unroll 4
  for (int j = 0; j < 64; ++j) {
    float p0 = sS[(rb + 0) * 65 + j], p1 = sS[(rb + 1) * 65 + j];
    float p2 = sS[(rb + 2) * 65 + j], p3 = sS[(rb + 3) * 65 + j];
    #pragma unroll
    for (int q = 0; q < 4; ++q) {
      float vq = sQ[j * 65 + c4 * 4 + q];
      pv[0][q] = fmaf(p0, vq, pv[0][q]); pv[1][q] = fmaf(p1, vq, pv[1][q]);
      pv[2][q] = fmaf(p2, vq, pv[2][q]); pv[3][q] = fmaf(p3, vq, pv[3][q]);
    }
  }
  #pragma unroll
  for (int i = 0; i < 4; ++i)
    #pragma unroll
    for (int q = 0; q < 4; ++q)
      sK[(rb + i) * 65 + c4 * 4 + q] = pv[i][q];   // PV -> sK (K dead)
  __syncthreads();
  const float* Ad = A_dyn + br * 4096;
  for (int idx = t; idx < 4096; idx += 256)        // A_dyn -> sS (P dead)
    sS[(idx >> 6) * 65 + (idx & 63)] = Ad[idx];
  __syncthreads();
  float zz[4][4] = {};
  #pragma unroll 4
  for (int j = 0; j < 64; ++j) {
    float a0 = sS[(rb + 0) * 65 + j], a1 = sS[(rb + 1) * 65 + j];
    float a2 = sS[(rb + 2) * 65 + j], a3 = sS[(rb + 3) * 65 + j];
    #pragma unroll
    for (int q = 0; q < 4; ++q) {
      float p = sK[j * 65 + c4 * 4 + q];
      zz[0][q] = fmaf(a0, p, zz[0][q]); zz[1][q] = fmaf(a1, p, zz[1][q]);
      zz[2][q] = fmaf(a2, p, zz[2][q]); zz[3][q] = fmaf(a3, p, zz[3][q]);
    }
  }
  long zbase = ((long)(b0 + b) * 64) * 192 + br * 64;
  #pragma unroll
  for (int i = 0; i < 4; ++i) {
    float4 o; o.x = zz[i][0]; o.y = zz[i][1]; o.z = zz[i][2]; o.w = zz[i][3];
    *(float4*)&Zl[zbase + (long)(rb + i) * 192 + c4 * 4] = o;
  }
}

// ---------------- fusion: Z_global, cw softmax, Zg, LayerNorm ----------------
__global__ __launch_bounds__(256) void k_fuse(
    const float* __restrict__ Zl, const float* __restrict__ A_init,
    const float* __restrict__ ln_g, const float* __restrict__ ln_b,
    float* __restrict__ Zg_out, float* __restrict__ Zln_out)
{
  int b = blockIdx.x, t = threadIdx.x;
  __shared__ float sZ[64 * 192];   // 48 KB
  __shared__ float sAT[64 * 64];   // 16 KB (first colmeans, then A_init^T)
  const float* Zb = Zl + (long)b * 64 * 192;
  for (int idx = t * 4; idx < 12288; idx += 1024)
    *(float4*)&sZ[idx] = *(const float4*)&Zb[idx];
  __syncthreads();
  if (t < 192) {
    float s = 0.f;
    #pragma unroll 8
    for (int j = 0; j < 64; ++j) s += sZ[j * 192 + t];
    sAT[t] = s * (1.f / 64.f);
  }
  __syncthreads();
  float m = -3.4e38f;
  for (int d = 0; d < 192; ++d) m = fmaxf(m, sAT[d]);
  float ssum = 0.f;
  for (int d = 0; d < 192; ++d) ssum += expf(sAT[d] - m);
  float cinv = 1.f / ssum;
  int c4 = t & 15, rb = (t >> 4) * 4;
  float cw[12];
  #pragma unroll
  for (int cc = 0; cc < 3; ++cc)
    #pragma unroll
    for (int q = 0; q < 4; ++q)
      cw[cc * 4 + q] = expf(sAT[cc * 64 + c4 * 4 + q] - m) * cinv;
  __syncthreads();
  for (int idx = t; idx < 4096; idx += 256)
    sAT[(idx & 63) * 64 + (idx >> 6)] = A_init[idx];
  __syncthreads();
  float acc[3][4][4] = {};
  for (int j = 0; j < 64; ++j) {
    float a0 = sAT[j * 64 + rb + 0], a1 = sAT[j * 64 + rb + 1];
    float a2 = sAT[j * 64 + rb + 2], a3 = sAT[j * 64 + rb + 3];
    #pragma unroll
    for (int cc = 0; cc < 3; ++cc) {
      float4 zv = *(const float4*)&sZ[j * 192 + cc * 64 + c4 * 4];
      acc[cc][0][0] = fmaf(a0, zv.x, acc[cc][0][0]); acc[cc][0][1] = fmaf(a0, zv.y, acc[cc][0][1]);
      acc[cc][0][2] = fmaf(a0, zv.z, acc[cc][0][2]); acc[cc][0][3] = fmaf(a0, zv.w, acc[cc][0][3]);
      acc[cc][1][0] = fmaf(a1, zv.x, acc[cc][1][0]); acc[cc][1][1] = fmaf(a1, zv.y, acc[cc][1][1]);
      acc[cc][1][2] = fmaf(a1, zv.z, acc[cc][1][2]); acc[cc][1][3] = fmaf(a1, zv.w, acc[cc][1][3]);
      acc[cc][2][0] = fmaf(a2, zv.x, acc[cc][2][0]); acc[cc][2][1] = fmaf(a2, zv.y, acc[cc][2][1]);
      acc[cc][2][2] = fmaf(a2, zv.z, acc[cc][2][2]); acc[cc][2][3] = fmaf(a2, zv.w, acc[cc][2][3]);
      acc[cc][3][0] = fmaf(a3, zv.x, acc[cc][3][0]); acc[cc][3][1] = fmaf(a3, zv.y, acc[cc][3][1]);
      acc[cc][3][2] = fmaf(a3, zv.z, acc[cc][3][2]); acc[cc][3][3] = fmaf(a3, zv.w, acc[cc][3][3]);
    }
  }
  long obase = (long)b * 64 * 192;
  #pragma unroll
  for (int cc = 0; cc < 3; ++cc)
    #pragma unroll
    for (int i = 0; i < 4; ++i)
      #pragma unroll
      for (int q = 0; q < 4; ++q)
        acc[cc][i][q] *= cw[cc * 4 + q];
  #pragma unroll
  for (int cc = 0; cc < 3; ++cc)
    #pragma unroll
    for (int i = 0; i < 4; ++i) {
      float4 o; o.x = acc[cc][i][0]; o.y = acc[cc][i][1]; o.z = acc[cc][i][2]; o.w = acc[cc][i][3];
      *(float4*)&Zg_out[obase + (long)(rb + i) * 192 + cc * 64 + c4 * 4] = o;
    }
  __syncthreads();   // all sZ reads done
  #pragma unroll
  for (int cc = 0; cc < 3; ++cc)
    #pragma unroll
    for (int i = 0; i < 4; ++i) {
      float4 o; o.x = acc[cc][i][0]; o.y = acc[cc][i][1]; o.z = acc[cc][i][2]; o.w = acc[cc][i][3];
      *(float4*)&sZ[(rb + i) * 192 + cc * 64 + c4 * 4] = o;
    }
  __syncthreads();
  {  // LayerNorm per row; 4 threads/row; rotate col start by r to spread banks
    int r = t >> 2, l = t & 3;
    float s = 0.f, s2 = 0.f;
    for (int ci = 0; ci < 48; ++ci) {
      int c = ci + r; if (c >= 48) c -= 48;
      float v = sZ[r * 192 + l * 48 + c];
      s += v; s2 = fmaf(v, v, s2);
    }
    s  += __shfl_xor(s, 1);  s  += __shfl_xor(s, 2);
    s2 += __shfl_xor(s2, 1); s2 += __shfl_xor(s2, 2);
    float mu = s * (1.f / 192.f);
    float var = s2 * (1.f / 192.f) - mu * mu;
    float rstd = rsqrtf(var + 1e-5f);
    for (int ci = 0; ci < 48; ++ci) {
      int c = ci + r; if (c >= 48) c -= 48;
      int d = l * 48 + c;
      float v = sZ[r * 192 + d];
      Zln_out[obase + (long)r * 192 + d] = (v - mu) * rstd * ln_g[d] + ln_b[d];
    }
  }
}

// ---------------- output head finalize: sum split-K partials, relu, logits ----------------
__global__ __launch_bounds__(128) void k_final(
    const float* __restrict__ partial, const float* __restrict__ o1b,
    const float* __restrict__ o2w, const float* __restrict__ o2b,
    float* __restrict__ logits, int nsplit)
{
  int b = blockIdx.x, t = threadIdx.x;
  __shared__ float sH[128];
  float a = o1b[t];
  for (int s = 0; s < nsplit; ++s) a += partial[(long)s * 512 * 128 + b * 128 + t];
  a = fmaxf(a, 0.f);
  sH[t] = a;
  __syncthreads();
  if (t < 2) {
    float z = o2b[t];
    #pragma unroll 8
    for (int h = 0; h < 128; ++h) z = fmaf(sH[h], o2w[h * 2 + t], z);
    logits[b * 2 + t] = z;
  }
}

extern "C" void kernel_launch(void* const* d_in, const int* in_sizes, int n_in,
                              void* d_out, int out_size, void* d_ws, size_t ws_size,
                              hipStream_t stream)
{
  const float* x      = (const float*)d_in[0];
  const float* A_init = (const float*)d_in[1];
  const float* f1w = (const float*)d_in[2];
  const float* f1b = (const float*)d_in[3];
  const float* f2w = (const float*)d_in[4];
  const float* f2b = (const float*)d_in[5];
  const float* q1w = (const float*)d_in[6];
  const float* q1b = (const float*)d_in[7];
  const float* q2w = (const float*)d_in[8];
  const float* q2b = (const float*)d_in[9];
  const float* wqw = (const float*)d_in[10];
  const float* wqb = (const float*)d_in[11];
  const float* wkw = (const float*)d_in[12];
  const float* wkb = (const float*)d_in[13];
  const float* wvw = (const float*)d_in[14];
  const float* wvb = (const float*)d_in[15];
  const float* lng = (const float*)d_in[16];
  const float* lnb = (const float*)d_in[17];
  const float* fc1w = (const float*)d_in[18];
  const float* fc1b = (const float*)d_in[19];
  const float* fc2w = (const float*)d_in[20];
  const float* fc2b = (const float*)d_in[21];
  const float* fm1w = (const float*)d_in[22];
  const float* fm1b = (const float*)d_in[23];
  const float* fm2w = (const float*)d_in[24];
  const float* fm2b = (const float*)d_in[25];
  const float* o1w  = (const float*)d_in[26];
  const float* o1b  = (const float*)d_in[27];
  const float* o2w  = (const float*)d_in[28];
  const float* o2b  = (const float*)d_in[29];

  float* outF   = (float*)d_out;
  float* logits = outF;                 // 512*2
  float* Zfused = outF + 1024;          // 512*64*192

  float* ws     = (float*)d_ws;
  float* A_dyn  = ws;                   // 3*4096
  float* A_norm = ws + 12288;           // 3*4096
  float* pool   = ws + 32768;

  // Adaptive chunk size over batches (deterministic: depends only on ws_size).
  int NB = 512;
  for (;; NB >>= 1) {
    long sb = (long)3 * NB * 64 * 512;
    long need = 32768 + 2 * sb + NZv + 3 * NZv + (long)24 * 512 * 128 + 1024;
    if (need * 4 <= (long)ws_size || NB == 16) break;
  }
  long SB = (long)3 * NB * 64 * 512;
  long CM = (long)NB * 64;              // rows per chunk per branch
  float* bufA    = pool;
  float* bufB    = bufA + SB;
  float* Zl      = bufB + SB;           // full (B,C,192)
  float* s1      = Zl + NZv;            // Zg
  float* s2      = s1 + NZv;            // Zln, later Zfc
  float* s3      = s2 + NZv;            // t2, later t3
  float* partial = s3 + NZv;            // 24*512*128

  k_dyngraph<<<dim3(3), dim3(256), 0, stream>>>(A_init, f1w, f1b, f2w, f2b, A_dyn, A_norm);

  for (int b0 = 0; b0 < Bn; b0 += NB) {
    const float* xc = x + (long)b0 * 64 * 512;
    // t_a = elu(x@q1w + b)  -> bufA
    k_gemm<2, false, false><<<dim3(8, NB, 3), 256, 0, stream>>>(
        (int)CM, 512, 512, xc, BCD, 512, q1w, (long)512 * 512, q1b, 512,
        bufA, CM * 512, nullptr, 0);
    // h = t_a@q2w + b  -> bufB
    k_gemm<0, false, false><<<dim3(8, NB, 3), 256, 0, stream>>>(
        (int)CM, 512, 512, bufA, CM * 512, 512, q2w, (long)512 * 512, q2b, 512,
        bufB, CM * 512, nullptr, 0);
    // G = elu(A_norm@h + x)  -> bufA
    k_diffuse<<<dim3(NB, 3), 256, 0, stream>>>(A_norm, bufB, x, bufA, b0, NB);
    // Q,K,V -> bufB
    float* Qc = bufB;
    float* Kc = bufB + 3 * CM * 64;
    float* Vc = bufB + 6 * CM * 64;
    k_gemm<0, false, false><<<dim3(1, NB, 3), 256, 0, stream>>>(
        (int)CM, 64, 512, bufA, CM * 512, 512, wqw, (long)512 * 64, wqb, 64,
        Qc, CM * 64, nullptr, 0);
    k_gemm<0, false, false><<<dim3(1, NB, 3), 256, 0, stream>>>(
        (int)CM, 64, 512, bufA, CM * 512, 512, wkw, (long)512 * 64, wkb, 64,
        Kc, CM * 64, nullptr, 0);
    k_gemm<0, false, false><<<dim3(1, NB, 3), 256, 0, stream>>>(
        (int)CM, 64, 512, bufA, CM * 512, 512, wvw, (long)512 * 64, wvb, 64,
        Vc, CM * 64, nullptr, 0);
    // attention + A_dyn apply -> Zl (concat layout)
    k_attn<<<dim3(NB, 3), 256, 0, stream>>>(Qc, Kc, Vc, A_dyn, Zl, b0, NB);
  }

  // fusion: Zg -> s1, Z_ln -> s2
  k_fuse<<<dim3(Bn), 256, 0, stream>>>(Zl, A_init, lng, lnb, s1, s2);
  // t2 = relu(Zln@fc1+b) -> s3
  k_gemm<1, false, false><<<dim3(3, 512, 1), 256, 0, stream>>>(
      MTOT, 192, 192, s2, 0, 192, fc1w, 0, fc1b, 0, s3, 0, nullptr, 0);
  // Zfc = t2@fc2+b -> s2 (Zln dead)
  k_gemm<0, false, false><<<dim3(3, 512, 1), 256, 0, stream>>>(
      MTOT, 192, 192, s3, 0, 192, fc2w, 0, fc2b, 0, s2, 0, nullptr, 0);
  // t3 = elu(Zg@fm1+b) -> s3 (t2 dead)
  k_gemm<2, false, false><<<dim3(3, 512, 1), 256, 0, stream>>>(
      MTOT, 192, 192, s1, 0, 192, fm1w, 0, fm1b, 0, s3, 0, nullptr, 0);
  // Z_fused = t3@fm2+b + Zfc -> d_out (offset 1024)
  k_gemm<0, true, false><<<dim3(3, 512, 1), 256, 0, stream>>>(
      MTOT, 192, 192, s3, 0, 192, fm2w, 0, fm2b, 0, Zfused, 0, s2, 0);
  // output head: split-K GEMM (512 x 128, K=12288, 24 chunks of 512)
  k_gemm<0, false, true><<<dim3(2, 8, 24), 256, 0, stream>>>(
      512, 128, 12288, Zfused, 0, 12288, o1w, 0, nullptr, 0,
      partial, (long)512 * 128, nullptr, 512);
  k_final<<<dim3(512), 128, 0, stream>>>(partial, o1b, o2w, o2b, logits, 24);
}

// Round 2
// 1848.235 us; speedup vs baseline: 1.5005x; 1.5005x over previous
//
#include <hip/hip_runtime.h>
#include <math.h>

typedef unsigned short u16;
typedef __attribute__((ext_vector_type(8))) short short8;
typedef __attribute__((ext_vector_type(4))) float f32x4;
typedef __attribute__((ext_vector_type(4))) unsigned short u16x4;

// Problem dims
constexpr int  Bn   = 512;              // batches
constexpr int  Cch  = 64;               // EEG channels
constexpr int  Dd   = 512;              // feature dim
constexpr int  DV3  = 192;              // 3*DV
constexpr long BCD  = (long)Bn * Cch * Dd;     // per-branch x elements
constexpr int  MTOT = Bn * Cch;                // 32768
constexpr long NZv  = (long)Bn * Cch * DV3;    // 6,291,456

__device__ __forceinline__ float eluf(float v) { return v > 0.f ? v : expm1f(v); }

__device__ __forceinline__ u16 f2bf(float f) {
  unsigned u = __float_as_uint(f);
  unsigned r = u + 0x7fffu + ((u >> 16) & 1u);
  return (u16)(r >> 16);
}
__device__ __forceinline__ float bf2f(u16 h) { return __uint_as_float(((unsigned)h) << 16); }

typedef __attribute__((address_space(1))) const unsigned int gu32;
typedef __attribute__((address_space(3))) unsigned int lu32;
__device__ __forceinline__ void g2l16(const void* g, void* l) {
  __builtin_amdgcn_global_load_lds((gu32*)g, (lu32*)l, 16, 0, 0);
}

// ---------------- dynamic graph: A_dyn / A_norm (3 blocks) ----------------
__global__ __launch_bounds__(256) void k_dyngraph(
    const float* __restrict__ A_init,
    const float* __restrict__ f1w, const float* __restrict__ f1b,
    const float* __restrict__ f2w, const float* __restrict__ f2b,
    float* __restrict__ A_dyn, float* __restrict__ A_norm)
{
  int br = blockIdx.x, t = threadIdx.x;
  __shared__ float sA[4096];
  __shared__ float sMid[256];
  __shared__ float sDyn[4096];
  __shared__ float sSum[64];
  for (int i = t; i < 4096; i += 256) sA[i] = A_init[i];
  __syncthreads();
  const float* w1 = f1w + (long)br * 4096 * 256;
  float acc = f1b[br * 256 + t];
  #pragma unroll 8
  for (int k = 0; k < 4096; ++k) acc = fmaf(sA[k], w1[(long)k * 256 + t], acc);
  sMid[t] = eluf(acc);
  __syncthreads();
  const float* w2 = f2w + (long)br * 256 * 4096;
  const float* b2 = f2b + br * 4096;
  for (int j = t; j < 4096; j += 256) {
    float a = b2[j];
    #pragma unroll 8
    for (int k = 0; k < 256; ++k) a = fmaf(sMid[k], w2[(long)k * 4096 + j], a);
    a = fmaxf(a, 0.f);
    sDyn[j] = a;
    A_dyn[br * 4096 + j] = a;
  }
  __syncthreads();
  if (t < 64) {
    float s = 0.f;
    for (int j = 0; j < 64; ++j) s += sDyn[t * 64 + j];
    sSum[t] = s + 1e-6f;
  }
  __syncthreads();
  for (int j = t; j < 4096; j += 256)
    A_norm[br * 4096 + j] = sDyn[j] / sSum[j >> 6];
}

// ---------------- conversion kernels: f32 -> hi/lo bf16 ----------------
__global__ __launch_bounds__(256) void k_cvt_x(
    const float* __restrict__ src, long s_zs,
    u16* __restrict__ hi, u16* __restrict__ lo, long d_zs, long n)
{
  int z = blockIdx.y;
  long i = ((long)blockIdx.x * 256 + threadIdx.x) * 4;
  if (i >= n) return;
  float4 v = *(const float4*)&src[z * s_zs + i];
  u16x4 h, l;
  h.x = f2bf(v.x); l.x = f2bf(v.x - bf2f(h.x));
  h.y = f2bf(v.y); l.y = f2bf(v.y - bf2f(h.y));
  h.z = f2bf(v.z); l.z = f2bf(v.z - bf2f(h.z));
  h.w = f2bf(v.w); l.w = f2bf(v.w - bf2f(h.w));
  *(u16x4*)&hi[z * d_zs + i] = h;
  *(u16x4*)&lo[z * d_zs + i] = l;
}

// weights (z,K,N) f32 -> (z,N,K) hi/lo bf16 (transposed)
__global__ __launch_bounds__(256) void k_cvt_wT(
    const float* __restrict__ w, u16* __restrict__ hT, u16* __restrict__ lT,
    int K, int N)
{
  long idx = (long)blockIdx.x * 256 + threadIdx.x;
  long tot = (long)3 * N * K;
  if (idx >= tot) return;
  int z = (int)(idx / ((long)N * K));
  long r = idx % ((long)N * K);
  int n = (int)(r / K), k = (int)(r % K);
  float v = w[((long)z * K + k) * N + n];
  u16 h = f2bf(v);
  hT[idx] = h;
  lT[idx] = f2bf(v - bf2f(h));
}

// concat wq|wk|wv (each (z,512,64)) -> (z,256,512) transposed hi/lo, rows 192..255 zero
__global__ __launch_bounds__(256) void k_cvt_qkvT(
    const float* __restrict__ wq, const float* __restrict__ wk, const float* __restrict__ wv,
    u16* __restrict__ hT, u16* __restrict__ lT)
{
  long idx = (long)blockIdx.x * 256 + threadIdx.x;
  long tot = (long)3 * 256 * 512;
  if (idx >= tot) return;
  int z = (int)(idx / (256 * 512));
  long r = idx % (256 * 512);
  int n = (int)(r / 512), k = (int)(r % 512);
  float v = 0.f;
  if (n < 64)       v = wq[((long)z * 512 + k) * 64 + n];
  else if (n < 128) v = wk[((long)z * 512 + k) * 64 + (n - 64)];
  else if (n < 192) v = wv[((long)z * 512 + k) * 64 + (n - 128)];
  u16 h = f2bf(v);
  hT[idx] = h;
  lT[idx] = f2bf(v - bf2f(h));
}

__global__ __launch_bounds__(256) void k_cvt_qkvb(
    const float* __restrict__ bq, const float* __restrict__ bk, const float* __restrict__ bv,
    float* __restrict__ bcat)
{
  int idx = blockIdx.x * 256 + threadIdx.x;   // 3*256
  if (idx >= 768) return;
  int z = idx >> 8, n = idx & 255;
  float v = 0.f;
  if (n < 64)       v = bq[z * 64 + n];
  else if (n < 128) v = bk[z * 64 + (n - 64)];
  else if (n < 192) v = bv[z * 64 + (n - 128)];
  bcat[idx] = v;
}

// ---------------- split-bf16 MFMA GEMM ----------------
// A: hi/lo bf16 (z, M, K) row-major.  B: hi/lo bf16 (z, N, K) row-major (i.e. W^T).
// C = A@B^T + bias, 3-pass split: AhBh + AhBl + AlBh.
// Tile 128x128, BK=32, 4 waves (2x2 of 64x64), fragment-packed LDS via global_load_lds.
// ACT: 0 none, 2 elu.  OMODE: 0 -> f32 out (ldo), 1 -> bf16 hi/lo out (ldo).
template<int ACT, int OMODE>
__global__ __launch_bounds__(256) void k_mgemm(
    int M, int N, int K, int ldo,
    const u16* __restrict__ Ah, const u16* __restrict__ Al, long a_zs,
    const u16* __restrict__ Bh, const u16* __restrict__ Bl, long b_zs,
    const float* __restrict__ bias, long bias_zs,
    float* __restrict__ outF, u16* __restrict__ outH, u16* __restrict__ outL, long o_zs)
{
  int z  = blockIdx.z;
  int m0 = blockIdx.y * 128, n0 = blockIdx.x * 128;
  const u16* ah = Ah + z * a_zs;
  const u16* al = Al + z * a_zs;
  const u16* bh = Bh + z * b_zs;
  const u16* bl = Bl + z * b_zs;

  __shared__ u16 sAh[4096];   // 8 mb-blocks x 64 lanes x 8 bf16 (fragment-packed)
  __shared__ u16 sAl[4096];
  __shared__ u16 sBh[4096];
  __shared__ u16 sBl[4096];

  int t = threadIdx.x, wv = t >> 6, ln = t & 63;
  int mh = wv >> 1, nh = wv & 1;
  f32x4 acc[4][4] = {};

  // staging source select (wave-uniform)
  const u16* gsrc = (wv == 0) ? ah : (wv == 1) ? al : (wv == 2) ? bh : bl;
  u16* sdst = (wv == 0) ? sAh : (wv == 1) ? sAl : (wv == 2) ? sBh : sBl;
  int rbase = (wv < 2) ? m0 : n0;
  // per-lane source row/k-offset for fragment packing
  long lrow = rbase + (ln & 15);
  int  lk   = (ln >> 4) * 8;

  for (int kt = 0; kt < K; kt += 32) {
    const u16* g = gsrc + lrow * K + kt + lk;
    #pragma unroll
    for (int mb = 0; mb < 8; ++mb)
      g2l16(g + (long)mb * 16 * K, sdst + mb * 512);
    asm volatile("s_waitcnt vmcnt(0)" ::: "memory");
    __syncthreads();

    short8 a_h[4], a_l[4], b_h[4], b_l[4];
    #pragma unroll
    for (int f = 0; f < 4; ++f) {
      a_h[f] = *(const short8*)&sAh[(mh * 4 + f) * 512 + ln * 8];
      a_l[f] = *(const short8*)&sAl[(mh * 4 + f) * 512 + ln * 8];
      b_h[f] = *(const short8*)&sBh[(nh * 4 + f) * 512 + ln * 8];
      b_l[f] = *(const short8*)&sBl[(nh * 4 + f) * 512 + ln * 8];
    }
    #pragma unroll
    for (int i = 0; i < 4; ++i)
      #pragma unroll
      for (int j = 0; j < 4; ++j) {
        acc[i][j] = __builtin_amdgcn_mfma_f32_16x16x32_bf16(a_h[i], b_h[j], acc[i][j], 0, 0, 0);
        acc[i][j] = __builtin_amdgcn_mfma_f32_16x16x32_bf16(a_h[i], b_l[j], acc[i][j], 0, 0, 0);
        acc[i][j] = __builtin_amdgcn_mfma_f32_16x16x32_bf16(a_l[i], b_h[j], acc[i][j], 0, 0, 0);
      }
    __syncthreads();
  }

  int colb = n0 + nh * 64, rowb = m0 + mh * 64;
  #pragma unroll
  for (int i = 0; i < 4; ++i) {
    #pragma unroll
    for (int j = 0; j < 4; ++j) {
      int col = colb + j * 16 + (ln & 15);
      float bv = bias[z * bias_zs + col];
      #pragma unroll
      for (int r = 0; r < 4; ++r) {
        long row = rowb + i * 16 + (ln >> 4) * 4 + r;
        float v = acc[i][j][r] + bv;
        if (ACT == 2) v = eluf(v);
        if (OMODE == 0) {
          outF[z * o_zs + row * ldo + col] = v;
        } else {
          u16 h = f2bf(v);
          outH[z * o_zs + row * ldo + col] = h;
          outL[z * o_zs + row * ldo + col] = f2bf(v - bf2f(h));
        }
      }
    }
  }
}

// ---------------- graph diffusion: G = elu(A_norm @ h + x) -> hi/lo bf16 ----------------
__global__ __launch_bounds__(256) void k_diffuse(
    const float* __restrict__ A_norm, const float* __restrict__ h,
    const float* __restrict__ x, u16* __restrict__ Gh, u16* __restrict__ Gl,
    int b0, int NB)
{
  int b = blockIdx.x, br = blockIdx.y, t = threadIdx.x;
  __shared__ float sAT[64 * 64];
  __shared__ float sH[64 * 64];
  const float* An = A_norm + br * 4096;
  for (int idx = t; idx < 4096; idx += 256)
    sAT[(idx & 63) * 64 + (idx >> 6)] = An[idx];
  const float* hb = h + ((long)br * NB + b) * (64 * 512);
  const float* xb = x + ((long)br * Bn + (b0 + b)) * (64 * 512);
  u16* Ghb = Gh + ((long)br * NB + b) * (64 * 512);
  u16* Glb = Gl + ((long)br * NB + b) * (64 * 512);
  int c4 = t & 15, rb = (t >> 4) * 4;
  for (int dc = 0; dc < 512; dc += 64) {
    __syncthreads();
    for (int idx = t * 4; idx < 4096; idx += 1024) {
      int r = idx >> 6, c = idx & 63;
      *(float4*)&sH[idx] = *(const float4*)&hb[(long)r * 512 + dc + c];
    }
    __syncthreads();
    float acc[4][4] = {};
    #pragma unroll 4
    for (int j = 0; j < 64; ++j) {
      float a0 = sAT[j * 64 + rb + 0], a1 = sAT[j * 64 + rb + 1];
      float a2 = sAT[j * 64 + rb + 2], a3 = sAT[j * 64 + rb + 3];
      float4 hv = *(const float4*)&sH[j * 64 + c4 * 4];
      acc[0][0] = fmaf(a0, hv.x, acc[0][0]); acc[0][1] = fmaf(a0, hv.y, acc[0][1]);
      acc[0][2] = fmaf(a0, hv.z, acc[0][2]); acc[0][3] = fmaf(a0, hv.w, acc[0][3]);
      acc[1][0] = fmaf(a1, hv.x, acc[1][0]); acc[1][1] = fmaf(a1, hv.y, acc[1][1]);
      acc[1][2] = fmaf(a1, hv.z, acc[1][2]); acc[1][3] = fmaf(a1, hv.w, acc[1][3]);
      acc[2][0] = fmaf(a2, hv.x, acc[2][0]); acc[2][1] = fmaf(a2, hv.y, acc[2][1]);
      acc[2][2] = fmaf(a2, hv.z, acc[2][2]); acc[2][3] = fmaf(a2, hv.w, acc[2][3]);
      acc[3][0] = fmaf(a3, hv.x, acc[3][0]); acc[3][1] = fmaf(a3, hv.y, acc[3][1]);
      acc[3][2] = fmaf(a3, hv.z, acc[3][2]); acc[3][3] = fmaf(a3, hv.w, acc[3][3]);
    }
    #pragma unroll
    for (int i = 0; i < 4; ++i) {
      float4 xv = *(const float4*)&xb[(long)(rb + i) * 512 + dc + c4 * 4];
      float v0 = eluf(acc[i][0] + xv.x);
      float v1 = eluf(acc[i][1] + xv.y);
      float v2 = eluf(acc[i][2] + xv.z);
      float v3 = eluf(acc[i][3] + xv.w);
      u16x4 hh, ll;
      hh.x = f2bf(v0); ll.x = f2bf(v0 - bf2f(hh.x));
      hh.y = f2bf(v1); ll.y = f2bf(v1 - bf2f(hh.y));
      hh.z = f2bf(v2); ll.z = f2bf(v2 - bf2f(hh.z));
      hh.w = f2bf(v3); ll.w = f2bf(v3 - bf2f(hh.w));
      long o = (long)(rb + i) * 512 + dc + c4 * 4;
      *(u16x4*)&Ghb[o] = hh;
      *(u16x4*)&Glb[o] = ll;
    }
  }
}

// ---------------- attention + A_dyn apply, per (batch,branch) ----------------
// qkv layout: (3, NB*64, 256): cols 0-63 Q, 64-127 K, 128-191 V
__global__ __launch_bounds__(256) void k_attn(
    const float* __restrict__ qkv, const float* __restrict__ A_dyn,
    float* __restrict__ Zl, int b0, int NB)
{
  int b = blockIdx.x, br = blockIdx.y, t = threadIdx.x;
  __shared__ float sQ[64 * 65];
  __shared__ float sK[64 * 65];
  __shared__ float sS[64 * 65];
  const float* Qb = qkv + ((long)br * NB + b) * (64 * 256);
  for (int idx = t * 4; idx < 4096; idx += 1024) {
    int r = idx >> 6, c = idx & 63;
    float4 q4 = *(const float4*)&Qb[(long)r * 256 + c];
    float4 k4 = *(const float4*)&Qb[(long)r * 256 + 64 + c];
    sQ[r * 65 + c + 0] = q4.x; sQ[r * 65 + c + 1] = q4.y;
    sQ[r * 65 + c + 2] = q4.z; sQ[r * 65 + c + 3] = q4.w;
    sK[r * 65 + c + 0] = k4.x; sK[r * 65 + c + 1] = k4.y;
    sK[r * 65 + c + 2] = k4.z; sK[r * 65 + c + 3] = k4.w;
  }
  __syncthreads();
  int c4 = t & 15, rb = (t >> 4) * 4;
  float acc[4][4] = {};
  #pragma unroll 4
  for (int k = 0; k < 64; ++k) {
    float a0 = sQ[(rb + 0) * 65 + k], a1 = sQ[(rb + 1) * 65 + k];
    float a2 = sQ[(rb + 2) * 65 + k], a3 = sQ[(rb + 3) * 65 + k];
    #pragma unroll
    for (int q = 0; q < 4; ++q) {
      float bq = sK[(c4 * 4 + q) * 65 + k];
      acc[0][q] = fmaf(a0, bq, acc[0][q]); acc[1][q] = fmaf(a1, bq, acc[1][q]);
      acc[2][q] = fmaf(a2, bq, acc[2][q]); acc[3][q] = fmaf(a3, bq, acc[3][q]);
    }
  }
  #pragma unroll
  for (int i = 0; i < 4; ++i)
    #pragma unroll
    for (int q = 0; q < 4; ++q)
      sS[(rb + i) * 65 + c4 * 4 + q] = acc[i][q] * 0.125f;
  __syncthreads();
  {
    int r = t >> 2, l = t & 3;
    float m = -3.4e38f;
    #pragma unroll
    for (int c = 0; c < 16; ++c) m = fmaxf(m, sS[r * 65 + l * 16 + c]);
    m = fmaxf(m, __shfl_xor(m, 1));
    m = fmaxf(m, __shfl_xor(m, 2));
    float s = 0.f, e[16];
    #pragma unroll
    for (int c = 0; c < 16; ++c) { e[c] = expf(sS[r * 65 + l * 16 + c] - m); s += e[c]; }
    s += __shfl_xor(s, 1);
    s += __shfl_xor(s, 2);
    float inv = 1.f / s;
    #pragma unroll
    for (int c = 0; c < 16; ++c) sS[r * 65 + l * 16 + c] = e[c] * inv;
  }
  __syncthreads();
  for (int idx = t * 4; idx < 4096; idx += 1024) {
    int r = idx >> 6, c = idx & 63;
    float4 v4 = *(const float4*)&Qb[(long)r * 256 + 128 + c];
    sQ[r * 65 + c + 0] = v4.x; sQ[r * 65 + c + 1] = v4.y;
    sQ[r * 65 + c + 2] = v4.z; sQ[r * 65 + c + 3] = v4.w;
  }
  __syncthreads();
  float pv[4][4] = {};
  #pragma unroll 4
  for (int j = 0; j < 64; ++j) {
    float p0 = sS[(rb + 0) * 65 + j], p1 = sS[(rb + 1) * 65 + j];
    float p2 = sS[(rb + 2) * 65 + j], p3 = sS[(rb + 3) * 65 + j];
    #pragma unroll
    for (int q = 0; q < 4; ++q) {
      float vq = sQ[j * 65 + c4 * 4 + q];
      pv[0][q] = fmaf(p0, vq, pv[0][q]); pv[1][q] = fmaf(p1, vq, pv[1][q]);
      pv[2][q] = fmaf(p2, vq, pv[2][q]); pv[3][q] = fmaf(p3, vq, pv[3][q]);
    }
  }
  #pragma unroll
  for (int i = 0; i < 4; ++i)
    #pragma unroll
    for (int q = 0; q < 4; ++q)
      sK[(rb + i) * 65 + c4 * 4 + q] = pv[i][q];
  __syncthreads();
  const float* Ad = A_dyn + br * 4096;
  for (int idx = t; idx < 4096; idx += 256)
    sS[(idx >> 6) * 65 + (idx & 63)] = Ad[idx];
  __syncthreads();
  float zz[4][4] = {};
  #pragma unroll 4
  for (int j = 0; j < 64; ++j) {
    float a0 = sS[(rb + 0) * 65 + j], a1 = sS[(rb + 1) * 65 + j];
    float a2 = sS[(rb + 2) * 65 + j], a3 = sS[(rb + 3) * 65 + j];
    #pragma unroll
    for (int q = 0; q < 4; ++q) {
      float p = sK[j * 65 + c4 * 4 + q];
      zz[0][q] = fmaf(a0, p, zz[0][q]); zz[1][q] = fmaf(a1, p, zz[1][q]);
      zz[2][q] = fmaf(a2, p, zz[2][q]); zz[3][q] = fmaf(a3, p, zz[3][q]);
    }
  }
  long zbase = ((long)(b0 + b) * 64) * 192 + br * 64;
  #pragma unroll
  for (int i = 0; i < 4; ++i) {
    float4 o; o.x = zz[i][0]; o.y = zz[i][1]; o.z = zz[i][2]; o.w = zz[i][3];
    *(float4*)&Zl[zbase + (long)(rb + i) * 192 + c4 * 4] = o;
  }
}

// ---------------- generic f32 GEMM (fusion MLPs + head) ----------------
template<int ACT, bool RES, bool SPLITK>
__global__ __launch_bounds__(256) void k_gemm(
    int M, int N, int K,
    const float* __restrict__ A, long a_zs, int lda,
    const float* __restrict__ W, long w_zs,
    const float* __restrict__ bias, long b_zs,
    float* __restrict__ out, long o_zs,
    const float* __restrict__ resid, int k_chunk)
{
  int z  = blockIdx.z;
  int n0 = blockIdx.x * 64, m0 = blockIdx.y * 64;
  const float* Ab = A + (SPLITK ? 0 : z * a_zs);
  const float* Wb = W + (SPLITK ? 0 : z * w_zs);
  float* ob = out + z * o_zs;
  const float* bb = bias ? bias + z * b_zs : nullptr;
  const float* rb_ = RES ? resid + z * o_zs : nullptr;
  int k0   = SPLITK ? z * k_chunk : 0;
  int kend = SPLITK ? k0 + k_chunk : K;

  __shared__ float As[16][68];
  __shared__ float Bs[16][68];
  float acc[4][4] = {};
  int t  = threadIdx.x;
  int tm = t & 15, tn = t >> 4;
  int ar = t >> 2, ak = (t & 3) * 4;
  int bk = t >> 4, bn = (t & 15) * 4;

  for (int kt = k0; kt < kend; kt += 16) {
    float4 av = *(const float4*)&Ab[(long)(m0 + ar) * lda + kt + ak];
    float4 bv = *(const float4*)&Wb[(long)(kt + bk) * N + n0 + bn];
    __syncthreads();
    As[ak + 0][ar] = av.x; As[ak + 1][ar] = av.y;
    As[ak + 2][ar] = av.z; As[ak + 3][ar] = av.w;
    *(float4*)&Bs[bk][bn] = bv;
    __syncthreads();
    #pragma unroll
    for (int k = 0; k < 16; ++k) {
      float4 a = *(const float4*)&As[k][tm * 4];
      float4 b = *(const float4*)&Bs[k][tn * 4];
      acc[0][0] = fmaf(a.x, b.x, acc[0][0]); acc[0][1] = fmaf(a.x, b.y, acc[0][1]);
      acc[0][2] = fmaf(a.x, b.z, acc[0][2]); acc[0][3] = fmaf(a.x, b.w, acc[0][3]);
      acc[1][0] = fmaf(a.y, b.x, acc[1][0]); acc[1][1] = fmaf(a.y, b.y, acc[1][1]);
      acc[1][2] = fmaf(a.y, b.z, acc[1][2]); acc[1][3] = fmaf(a.y, b.w, acc[1][3]);
      acc[2][0] = fmaf(a.z, b.x, acc[2][0]); acc[2][1] = fmaf(a.z, b.y, acc[2][1]);
      acc[2][2] = fmaf(a.z, b.z, acc[2][2]); acc[2][3] = fmaf(a.z, b.w, acc[2][3]);
      acc[3][0] = fmaf(a.w, b.x, acc[3][0]); acc[3][1] = fmaf(a.w, b.y, acc[3][1]);
      acc[3][2] = fmaf(a.w, b.z, acc[3][2]); acc[3][3] = fmaf(a.w, b.w, acc[3][3]);
    }
  }

  #pragma unroll
  for (int i = 0; i < 4; ++i) {
    long row = m0 + tm * 4 + i;
    int  col = n0 + tn * 4;
    float v[4];
    #pragma unroll
    for (int j = 0; j < 4; ++j) {
      float x = acc[i][j] + (bb ? bb[col + j] : 0.f);
      if (ACT == 1) x = fmaxf(x, 0.f);
      if (ACT == 2) x = eluf(x);
      v[j] = x;
    }
    if (RES) {
      float4 r = *(const float4*)&rb_[row * N + col];
      v[0] += r.x; v[1] += r.y; v[2] += r.z; v[3] += r.w;
    }
    float4 o; o.x = v[0]; o.y = v[1]; o.z = v[2]; o.w = v[3];
    *(float4*)&ob[row * N + col] = o;
  }
}

// ---------------- fusion: Z_global, cw softmax, Zg, LayerNorm ----------------
__global__ __launch_bounds__(256) void k_fuse(
    const float* __restrict__ Zl, const float* __restrict__ A_init,
    const float* __restrict__ ln_g, const float* __restrict__ ln_b,
    float* __restrict__ Zg_out, float* __restrict__ Zln_out)
{
  int b = blockIdx.x, t = threadIdx.x;
  __shared__ float sZ[64 * 192];
  __shared__ float sAT[64 * 64];
  const float* Zb = Zl + (long)b * 64 * 192;
  for (int idx = t * 4; idx < 12288; idx += 1024)
    *(float4*)&sZ[idx] = *(const float4*)&Zb[idx];
  __syncthreads();
  if (t < 192) {
    float s = 0.f;
    #pragma unroll 8
    for (int j = 0; j < 64; ++j) s += sZ[j * 192 + t];
    sAT[t] = s * (1.f / 64.f);
  }
  __syncthreads();
  float m = -3.4e38f;
  for (int d = 0; d < 192; ++d) m = fmaxf(m, sAT[d]);
  float ssum = 0.f;
  for (int d = 0; d < 192; ++d) ssum += expf(sAT[d] - m);
  float cinv = 1.f / ssum;
  int c4 = t & 15, rb = (t >> 4) * 4;
  float cw[12];
  #pragma unroll
  for (int cc = 0; cc < 3; ++cc)
    #pragma unroll
    for (int q = 0; q < 4; ++q)
      cw[cc * 4 + q] = expf(sAT[cc * 64 + c4 * 4 + q] - m) * cinv;
  __syncthreads();
  for (int idx = t; idx < 4096; idx += 256)
    sAT[(idx & 63) * 64 + (idx >> 6)] = A_init[idx];
  __syncthreads();
  float acc[3][4][4] = {};
  for (int j = 0; j < 64; ++j) {
    float a0 = sAT[j * 64 + rb + 0], a1 = sAT[j * 64 + rb + 1];
    float a2 = sAT[j * 64 + rb + 2], a3 = sAT[j * 64 + rb + 3];
    #pragma unroll
    for (int cc = 0; cc < 3; ++cc) {
      float4 zv = *(const float4*)&sZ[j * 192 + cc * 64 + c4 * 4];
      acc[cc][0][0] = fmaf(a0, zv.x, acc[cc][0][0]); acc[cc][0][1] = fmaf(a0, zv.y, acc[cc][0][1]);
      acc[cc][0][2] = fmaf(a0, zv.z, acc[cc][0][2]); acc[cc][0][3] = fmaf(a0, zv.w, acc[cc][0][3]);
      acc[cc][1][0] = fmaf(a1, zv.x, acc[cc][1][0]); acc[cc][1][1] = fmaf(a1, zv.y, acc[cc][1][1]);
      acc[cc][1][2] = fmaf(a1, zv.z, acc[cc][1][2]); acc[cc][1][3] = fmaf(a1, zv.w, acc[cc][1][3]);
      acc[cc][2][0] = fmaf(a2, zv.x, acc[cc][2][0]); acc[cc][2][1] = fmaf(a2, zv.y, acc[cc][2][1]);
      acc[cc][2][2] = fmaf(a2, zv.z, acc[cc][2][2]); acc[cc][2][3] = fmaf(a2, zv.w, acc[cc][2][3]);
      acc[cc][3][0] = fmaf(a3, zv.x, acc[cc][3][0]); acc[cc][3][1] = fmaf(a3, zv.y, acc[cc][3][1]);
      acc[cc][3][2] = fmaf(a3, zv.z, acc[cc][3][2]); acc[cc][3][3] = fmaf(a3, zv.w, acc[cc][3][3]);
    }
  }
  long obase = (long)b * 64 * 192;
  #pragma unroll
  for (int cc = 0; cc < 3; ++cc)
    #pragma unroll
    for (int i = 0; i < 4; ++i)
      #pragma unroll
      for (int q = 0; q < 4; ++q)
        acc[cc][i][q] *= cw[cc * 4 + q];
  #pragma unroll
  for (int cc = 0; cc < 3; ++cc)
    #pragma unroll
    for (int i = 0; i < 4; ++i) {
      float4 o; o.x = acc[cc][i][0]; o.y = acc[cc][i][1]; o.z = acc[cc][i][2]; o.w = acc[cc][i][3];
      *(float4*)&Zg_out[obase + (long)(rb + i) * 192 + cc * 64 + c4 * 4] = o;
    }
  __syncthreads();
  #pragma unroll
  for (int cc = 0; cc < 3; ++cc)
    #pragma unroll
    for (int i = 0; i < 4; ++i) {
      float4 o; o.x = acc[cc][i][0]; o.y = acc[cc][i][1]; o.z = acc[cc][i][2]; o.w = acc[cc][i][3];
      *(float4*)&sZ[(rb + i) * 192 + cc * 64 + c4 * 4] = o;
    }
  __syncthreads();
  {
    int r = t >> 2, l = t & 3;
    float s = 0.f, s2 = 0.f;
    for (int ci = 0; ci < 48; ++ci) {
      int c = ci + r; if (c >= 48) c -= 48;
      float v = sZ[r * 192 + l * 48 + c];
      s += v; s2 = fmaf(v, v, s2);
    }
    s  += __shfl_xor(s, 1);  s  += __shfl_xor(s, 2);
    s2 += __shfl_xor(s2, 1); s2 += __shfl_xor(s2, 2);
    float mu = s * (1.f / 192.f);
    float var = s2 * (1.f / 192.f) - mu * mu;
    float rstd = rsqrtf(var + 1e-5f);
    for (int ci = 0; ci < 48; ++ci) {
      int c = ci + r; if (c >= 48) c -= 48;
      int d = l * 48 + c;
      float v = sZ[r * 192 + d];
      Zln_out[obase + (long)r * 192 + d] = (v - mu) * rstd * ln_g[d] + ln_b[d];
    }
  }
}

// ---------------- output head finalize ----------------
__global__ __launch_bounds__(128) void k_final(
    const float* __restrict__ partial, const float* __restrict__ o1b,
    const float* __restrict__ o2w, const float* __restrict__ o2b,
    float* __restrict__ logits, int nsplit)
{
  int b = blockIdx.x, t = threadIdx.x;
  __shared__ float sH[128];
  float a = o1b[t];
  for (int s = 0; s < nsplit; ++s) a += partial[(long)s * 512 * 128 + b * 128 + t];
  a = fmaxf(a, 0.f);
  sH[t] = a;
  __syncthreads();
  if (t < 2) {
    float z = o2b[t];
    #pragma unroll 8
    for (int h = 0; h < 128; ++h) z = fmaf(sH[h], o2w[h * 2 + t], z);
    logits[b * 2 + t] = z;
  }
}

extern "C" void kernel_launch(void* const* d_in, const int* in_sizes, int n_in,
                              void* d_out, int out_size, void* d_ws, size_t ws_size,
                              hipStream_t stream)
{
  const float* x      = (const float*)d_in[0];
  const float* A_init = (const float*)d_in[1];
  const float* f1w = (const float*)d_in[2];
  const float* f1b = (const float*)d_in[3];
  const float* f2w = (const float*)d_in[4];
  const float* f2b = (const float*)d_in[5];
  const float* q1w = (const float*)d_in[6];
  const float* q1b = (const float*)d_in[7];
  const float* q2w = (const float*)d_in[8];
  const float* q2b = (const float*)d_in[9];
  const float* wqw = (const float*)d_in[10];
  const float* wqb = (const float*)d_in[11];
  const float* wkw = (const float*)d_in[12];
  const float* wkb = (const float*)d_in[13];
  const float* wvw = (const float*)d_in[14];
  const float* wvb = (const float*)d_in[15];
  const float* lng = (const float*)d_in[16];
  const float* lnb = (const float*)d_in[17];
  const float* fc1w = (const float*)d_in[18];
  const float* fc1b = (const float*)d_in[19];
  const float* fc2w = (const float*)d_in[20];
  const float* fc2b = (const float*)d_in[21];
  const float* fm1w = (const float*)d_in[22];
  const float* fm1b = (const float*)d_in[23];
  const float* fm2w = (const float*)d_in[24];
  const float* fm2b = (const float*)d_in[25];
  const float* o1w  = (const float*)d_in[26];
  const float* o1b  = (const float*)d_in[27];
  const float* o2w  = (const float*)d_in[28];
  const float* o2b  = (const float*)d_in[29];

  float* outF   = (float*)d_out;
  float* logits = outF;                 // 512*2
  float* Zfused = outF + 1024;          // 512*64*192

  // ---- workspace layout (byte-based, 256B aligned) ----
  size_t off = 0;
  char* base = (char*)d_ws;
  auto alloc = [&](size_t bytes) -> void* {
    void* p = base + off;
    off += (bytes + 255) & ~(size_t)255;
    return p;
  };
  float* A_dyn  = (float*)alloc(3 * 4096 * 4);
  float* A_norm = (float*)alloc(3 * 4096 * 4);
  u16* q1T_h = (u16*)alloc((size_t)3 * 512 * 512 * 2);
  u16* q1T_l = (u16*)alloc((size_t)3 * 512 * 512 * 2);
  u16* q2T_h = (u16*)alloc((size_t)3 * 512 * 512 * 2);
  u16* q2T_l = (u16*)alloc((size_t)3 * 512 * 512 * 2);
  u16* qkvT_h = (u16*)alloc((size_t)3 * 256 * 512 * 2);
  u16* qkvT_l = (u16*)alloc((size_t)3 * 256 * 512 * 2);
  float* qkvb = (float*)alloc(3 * 256 * 4);
  float* Zl = (float*)alloc(NZv * 4);
  float* s1 = (float*)alloc(NZv * 4);
  float* s2 = (float*)alloc(NZv * 4);
  float* s3 = (float*)alloc(NZv * 4);
  float* partial = (float*)alloc((size_t)24 * 512 * 128 * 4);

  // chunk size: per NB batch -> xh/xl/th/tl (4 x 196608 B) + h (393216 B)
  int NB = 512;
  while (NB > 32) {
    size_t chunk = (size_t)NB * 1179648ULL;
    if (off + chunk + 8192 <= ws_size) break;
    NB >>= 1;
  }
  long CM  = (long)NB * 64;             // rows per chunk per branch
  long SBe = (long)3 * NB * 32768;      // elements per hi/lo array (3 branches)
  u16* xh = (u16*)alloc(SBe * 2);
  u16* xl = (u16*)alloc(SBe * 2);
  u16* th = (u16*)alloc(SBe * 2);
  u16* tl = (u16*)alloc(SBe * 2);
  float* hb = (float*)alloc(SBe * 4);   // h f32; reused as QKV f32 (needs half)
  u16* Gh = th;                          // reuse t_a after GEMM2
  u16* Gl = tl;
  float* qkvB = hb;                      // reuse h after diffuse

  k_dyngraph<<<dim3(3), dim3(256), 0, stream>>>(A_init, f1w, f1b, f2w, f2b, A_dyn, A_norm);
  k_cvt_wT<<<dim3(3072), 256, 0, stream>>>(q1w, q1T_h, q1T_l, 512, 512);
  k_cvt_wT<<<dim3(3072), 256, 0, stream>>>(q2w, q2T_h, q2T_l, 512, 512);
  k_cvt_qkvT<<<dim3(1536), 256, 0, stream>>>(wqw, wkw, wvw, qkvT_h, qkvT_l);
  k_cvt_qkvb<<<dim3(3), 256, 0, stream>>>(wqb, wkb, wvb, qkvb);

  for (int b0 = 0; b0 < Bn; b0 += NB) {
    const float* xc = x + (long)b0 * 64 * 512;
    long an = (long)NB * 32768;
    // split x chunk -> xh/xl
    k_cvt_x<<<dim3((unsigned)(an / 1024), 3), 256, 0, stream>>>(
        xc, BCD, xh, xl, an, an);
    // t_a = elu(x@q1w + b) -> th/tl (bf16 hi/lo)
    k_mgemm<2, 1><<<dim3(4, (unsigned)(CM / 128), 3), 256, 0, stream>>>(
        (int)CM, 512, 512, 512, xh, xl, an, q1T_h, q1T_l, (long)512 * 512,
        q1b, 512, nullptr, th, tl, an);
    // h = t_a@q2w + b -> hb (f32)
    k_mgemm<0, 0><<<dim3(4, (unsigned)(CM / 128), 3), 256, 0, stream>>>(
        (int)CM, 512, 512, 512, th, tl, an, q2T_h, q2T_l, (long)512 * 512,
        q2b, 512, hb, nullptr, nullptr, an);
    // G = elu(A_norm@h + x) -> Gh/Gl (reuses th/tl)
    k_diffuse<<<dim3(NB, 3), 256, 0, stream>>>(A_norm, hb, x, Gh, Gl, b0, NB);
    // QKV = G@Wqkv + b -> qkvB (f32, ld 256) (reuses hb)
    k_mgemm<0, 0><<<dim3(2, (unsigned)(CM / 128), 3), 256, 0, stream>>>(
        (int)CM, 256, 512, 256, Gh, Gl, an, qkvT_h, qkvT_l, (long)256 * 512,
        qkvb, 256, qkvB, nullptr, nullptr, CM * 256);
    // attention + A_dyn apply -> Zl
    k_attn<<<dim3(NB, 3), 256, 0, stream>>>(qkvB, A_dyn, Zl, b0, NB);
  }

  // fusion: Zg -> s1, Z_ln -> s2
  k_fuse<<<dim3(Bn), 256, 0, stream>>>(Zl, A_init, lng, lnb, s1, s2);
  k_gemm<1, false, false><<<dim3(3, 512, 1), 256, 0, stream>>>(
      MTOT, 192, 192, s2, 0, 192, fc1w, 0, fc1b, 0, s3, 0, nullptr, 0);
  k_gemm<0, false, false><<<dim3(3, 512, 1), 256, 0, stream>>>(
      MTOT, 192, 192, s3, 0, 192, fc2w, 0, fc2b, 0, s2, 0, nullptr, 0);
  k_gemm<2, false, false><<<dim3(3, 512, 1), 256, 0, stream>>>(
      MTOT, 192, 192, s1, 0, 192, fm1w, 0, fm1b, 0, s3, 0, nullptr, 0);
  k_gemm<0, true, false><<<dim3(3, 512, 1), 256, 0, stream>>>(
      MTOT, 192, 192, s3, 0, 192, fm2w, 0, fm2b, 0, Zfused, 0, s2, 0);
  k_gemm<0, false, true><<<dim3(2, 8, 24), 256, 0, stream>>>(
      512, 128, 12288, Zfused, 0, 12288, o1w, 0, nullptr, 0,
      partial, (long)512 * 128, nullptr, 512);
  k_final<<<dim3(512), 128, 0, stream>>>(partial, o1b, o2w, o2b, logits, 24);
}

// Round 3
// 1335.862 us; speedup vs baseline: 2.0760x; 1.3836x over previous
//
#include <hip/hip_runtime.h>
#include <math.h>

typedef unsigned short u16;
typedef __attribute__((ext_vector_type(8))) short short8;
typedef __attribute__((ext_vector_type(4))) float f32x4;
typedef __attribute__((ext_vector_type(4))) unsigned short u16x4;

// Problem dims
constexpr int  Bn   = 512;              // batches
constexpr int  Cch  = 64;               // EEG channels
constexpr int  Dd   = 512;              // feature dim
constexpr int  DV3  = 192;              // 3*DV
constexpr long BCD  = (long)Bn * Cch * Dd;     // per-branch x elements
constexpr int  MTOT = Bn * Cch;                // 32768
constexpr long NZv  = (long)Bn * Cch * DV3;    // 6,291,456

__device__ __forceinline__ float eluf(float v) { return v > 0.f ? v : expm1f(v); }

__device__ __forceinline__ u16 f2bf(float f) {
  unsigned u = __float_as_uint(f);
  unsigned r = u + 0x7fffu + ((u >> 16) & 1u);
  return (u16)(r >> 16);
}
__device__ __forceinline__ float bf2f(u16 h) { return __uint_as_float(((unsigned)h) << 16); }

typedef __attribute__((address_space(1))) const unsigned int gu32;
typedef __attribute__((address_space(3))) unsigned int lu32;
__device__ __forceinline__ void g2l16(const void* g, void* l) {
  __builtin_amdgcn_global_load_lds((gu32*)g, (lu32*)l, 16, 0, 0);
}

// ---------------- dynamic graph, parallelized ----------------
// stage 1: partial GEMV  pmid[z][kb][j] = sum_{k in kb-chunk} A[k] * w1[k*256+j]
__global__ __launch_bounds__(256) void k_dg1(
    const float* __restrict__ A_init, const float* __restrict__ f1w,
    float* __restrict__ pmid)
{
  int kb = blockIdx.x, z = blockIdx.y, t = threadIdx.x;
  __shared__ float sA[128];
  if (t < 128) sA[t] = A_init[kb * 128 + t];
  __syncthreads();
  const float* w1 = f1w + (long)z * 4096 * 256 + (long)kb * 128 * 256;
  float acc = 0.f;
  #pragma unroll 8
  for (int k = 0; k < 128; ++k) acc = fmaf(sA[k], w1[(long)k * 256 + t], acc);
  pmid[(z * 32 + kb) * 256 + t] = acc;
}

// stage 2: reduce partials, + bias, elu -> mid (3 x 256)
__global__ __launch_bounds__(256) void k_dg2(
    const float* __restrict__ pmid, const float* __restrict__ f1b,
    float* __restrict__ mid)
{
  int z = blockIdx.x, t = threadIdx.x;
  float s = f1b[z * 256 + t];
  #pragma unroll
  for (int kb = 0; kb < 32; ++kb) s += pmid[(z * 32 + kb) * 256 + t];
  mid[z * 256 + t] = eluf(s);
}

// stage 3: A_dyn = relu(mid @ w2 + b2); per-row sum; A_norm = A_dyn/(rowsum+1e-6)
// grid (16, 3); block 256 = 4 waves; wave w handles adjacency row jb*4+w (64 cols)
__global__ __launch_bounds__(256) void k_dg3(
    const float* __restrict__ mid, const float* __restrict__ f2w,
    const float* __restrict__ f2b,
    float* __restrict__ A_dyn, float* __restrict__ A_norm)
{
  int jb = blockIdx.x, z = blockIdx.y, t = threadIdx.x;
  __shared__ float sM[256];
  sM[t] = mid[z * 256 + t];
  __syncthreads();
  int j = jb * 256 + t;
  const float* w2 = f2w + (long)z * 256 * 4096;
  float acc = f2b[z * 4096 + j];
  #pragma unroll 8
  for (int k = 0; k < 256; ++k) acc = fmaf(sM[k], w2[(long)k * 4096 + j], acc);
  float a = fmaxf(acc, 0.f);
  A_dyn[z * 4096 + j] = a;
  // wave = one adjacency row (64 lanes = 64 cols): full 64-lane reduce
  float s = a;
  s += __shfl_xor(s, 1);  s += __shfl_xor(s, 2);  s += __shfl_xor(s, 4);
  s += __shfl_xor(s, 8);  s += __shfl_xor(s, 16); s += __shfl_xor(s, 32);
  A_norm[z * 4096 + j] = a / (s + 1e-6f);
}

// ---------------- conversion kernels: f32 -> hi/lo bf16 ----------------
__global__ __launch_bounds__(256) void k_cvt_x(
    const float* __restrict__ src, long s_zs,
    u16* __restrict__ hi, u16* __restrict__ lo, long d_zs, long n)
{
  int z = blockIdx.y;
  long i = ((long)blockIdx.x * 256 + threadIdx.x) * 4;
  if (i >= n) return;
  float4 v = *(const float4*)&src[z * s_zs + i];
  u16x4 h, l;
  h.x = f2bf(v.x); l.x = f2bf(v.x - bf2f(h.x));
  h.y = f2bf(v.y); l.y = f2bf(v.y - bf2f(h.y));
  h.z = f2bf(v.z); l.z = f2bf(v.z - bf2f(h.z));
  h.w = f2bf(v.w); l.w = f2bf(v.w - bf2f(h.w));
  *(u16x4*)&hi[z * d_zs + i] = h;
  *(u16x4*)&lo[z * d_zs + i] = l;
}

// weights (z,K,N) f32 -> (z,N,K) hi/lo bf16, tiled LDS transpose (coalesced both sides)
// grid (K/32, N/32, 3), block 256
__global__ __launch_bounds__(256) void k_cvt_wT(
    const float* __restrict__ w, u16* __restrict__ hT, u16* __restrict__ lT,
    int K, int N)
{
  int k0 = blockIdx.x * 32, n0 = blockIdx.y * 32, z = blockIdx.z;
  int t = threadIdx.x;
  __shared__ float sT[32][33];
  int tr = t >> 3, tc = (t & 7) * 4;
  float4 v = *(const float4*)&w[(long)z * K * N + (long)(k0 + tr) * N + n0 + tc];
  sT[tr][tc + 0] = v.x; sT[tr][tc + 1] = v.y; sT[tr][tc + 2] = v.z; sT[tr][tc + 3] = v.w;
  __syncthreads();
  u16x4 h, l;
  float a0 = sT[tc + 0][tr], a1 = sT[tc + 1][tr], a2 = sT[tc + 2][tr], a3 = sT[tc + 3][tr];
  h.x = f2bf(a0); l.x = f2bf(a0 - bf2f(h.x));
  h.y = f2bf(a1); l.y = f2bf(a1 - bf2f(h.y));
  h.z = f2bf(a2); l.z = f2bf(a2 - bf2f(h.z));
  h.w = f2bf(a3); l.w = f2bf(a3 - bf2f(h.w));
  long o = (long)z * N * K + (long)(n0 + tr) * K + k0 + tc;
  *(u16x4*)&hT[o] = h;
  *(u16x4*)&lT[o] = l;
}

// concat wq|wk|wv (each (z,512,64)) -> (z,256,512) transposed hi/lo, rows 192..255 zero
// grid (512/32=16, 256/32=8, 3), block 256
__global__ __launch_bounds__(256) void k_cvt_qkvT(
    const float* __restrict__ wq, const float* __restrict__ wk, const float* __restrict__ wv,
    u16* __restrict__ hT, u16* __restrict__ lT)
{
  int k0 = blockIdx.x * 32, n0 = blockIdx.y * 32, z = blockIdx.z;
  int t = threadIdx.x;
  int tr = t >> 3, tc = (t & 7) * 4;
  long o = (long)z * 256 * 512 + (long)(n0 + tr) * 512 + k0 + tc;
  if (n0 >= 192) {
    u16x4 zz = {0, 0, 0, 0};
    *(u16x4*)&hT[o] = zz;
    *(u16x4*)&lT[o] = zz;
    return;
  }
  const float* src = (n0 < 64) ? wq : (n0 < 128) ? wk : wv;
  int nsub = n0 & 63;
  __shared__ float sT[32][33];
  float4 v = *(const float4*)&src[(long)z * 512 * 64 + (long)(k0 + tr) * 64 + nsub + tc];
  sT[tr][tc + 0] = v.x; sT[tr][tc + 1] = v.y; sT[tr][tc + 2] = v.z; sT[tr][tc + 3] = v.w;
  __syncthreads();
  u16x4 h, l;
  float a0 = sT[tc + 0][tr], a1 = sT[tc + 1][tr], a2 = sT[tc + 2][tr], a3 = sT[tc + 3][tr];
  h.x = f2bf(a0); l.x = f2bf(a0 - bf2f(h.x));
  h.y = f2bf(a1); l.y = f2bf(a1 - bf2f(h.y));
  h.z = f2bf(a2); l.z = f2bf(a2 - bf2f(h.z));
  h.w = f2bf(a3); l.w = f2bf(a3 - bf2f(h.w));
  *(u16x4*)&hT[o] = h;
  *(u16x4*)&lT[o] = l;
}

__global__ __launch_bounds__(256) void k_cvt_qkvb(
    const float* __restrict__ bq, const float* __restrict__ bk, const float* __restrict__ bv,
    float* __restrict__ bcat)
{
  int idx = blockIdx.x * 256 + threadIdx.x;   // 3*256
  if (idx >= 768) return;
  int z = idx >> 8, n = idx & 255;
  float v = 0.f;
  if (n < 64)       v = bq[z * 64 + n];
  else if (n < 128) v = bk[z * 64 + (n - 64)];
  else if (n < 192) v = bv[z * 64 + (n - 128)];
  bcat[idx] = v;
}

// ---------------- split-bf16 MFMA GEMM ----------------
// A: hi/lo bf16 (z, M, K) row-major.  B: hi/lo bf16 (z, N, K) row-major (i.e. W^T).
// C = A@B^T + bias, 3-pass split: AhBh + AhBl + AlBh.
// Tile 128x128, BK=32, 4 waves (2x2 of 64x64), fragment-packed LDS via global_load_lds.
template<int ACT, int OMODE>
__global__ __launch_bounds__(256) void k_mgemm(
    int M, int N, int K, int ldo,
    const u16* __restrict__ Ah, const u16* __restrict__ Al, long a_zs,
    const u16* __restrict__ Bh, const u16* __restrict__ Bl, long b_zs,
    const float* __restrict__ bias, long bias_zs,
    float* __restrict__ outF, u16* __restrict__ outH, u16* __restrict__ outL, long o_zs)
{
  int z  = blockIdx.z;
  int m0 = blockIdx.y * 128, n0 = blockIdx.x * 128;
  const u16* ah = Ah + z * a_zs;
  const u16* al = Al + z * a_zs;
  const u16* bh = Bh + z * b_zs;
  const u16* bl = Bl + z * b_zs;

  __shared__ u16 sAh[4096];   // 8 mb-blocks x 64 lanes x 8 bf16 (fragment-packed)
  __shared__ u16 sAl[4096];
  __shared__ u16 sBh[4096];
  __shared__ u16 sBl[4096];

  int t = threadIdx.x, wv = t >> 6, ln = t & 63;
  int mh = wv >> 1, nh = wv & 1;
  f32x4 acc[4][4] = {};

  const u16* gsrc = (wv == 0) ? ah : (wv == 1) ? al : (wv == 2) ? bh : bl;
  u16* sdst = (wv == 0) ? sAh : (wv == 1) ? sAl : (wv == 2) ? sBh : sBl;
  int rbase = (wv < 2) ? m0 : n0;
  long lrow = rbase + (ln & 15);
  int  lk   = (ln >> 4) * 8;

  for (int kt = 0; kt < K; kt += 32) {
    const u16* g = gsrc + lrow * K + kt + lk;
    #pragma unroll
    for (int mb = 0; mb < 8; ++mb)
      g2l16(g + (long)mb * 16 * K, sdst + mb * 512);
    asm volatile("s_waitcnt vmcnt(0)" ::: "memory");
    __syncthreads();

    short8 a_h[4], a_l[4], b_h[4], b_l[4];
    #pragma unroll
    for (int f = 0; f < 4; ++f) {
      a_h[f] = *(const short8*)&sAh[(mh * 4 + f) * 512 + ln * 8];
      a_l[f] = *(const short8*)&sAl[(mh * 4 + f) * 512 + ln * 8];
      b_h[f] = *(const short8*)&sBh[(nh * 4 + f) * 512 + ln * 8];
      b_l[f] = *(const short8*)&sBl[(nh * 4 + f) * 512 + ln * 8];
    }
    #pragma unroll
    for (int i = 0; i < 4; ++i)
      #pragma unroll
      for (int j = 0; j < 4; ++j) {
        acc[i][j] = __builtin_amdgcn_mfma_f32_16x16x32_bf16(a_h[i], b_h[j], acc[i][j], 0, 0, 0);
        acc[i][j] = __builtin_amdgcn_mfma_f32_16x16x32_bf16(a_h[i], b_l[j], acc[i][j], 0, 0, 0);
        acc[i][j] = __builtin_amdgcn_mfma_f32_16x16x32_bf16(a_l[i], b_h[j], acc[i][j], 0, 0, 0);
      }
    __syncthreads();
  }

  int colb = n0 + nh * 64, rowb = m0 + mh * 64;
  #pragma unroll
  for (int i = 0; i < 4; ++i) {
    #pragma unroll
    for (int j = 0; j < 4; ++j) {
      int col = colb + j * 16 + (ln & 15);
      float bv = bias[z * bias_zs + col];
      #pragma unroll
      for (int r = 0; r < 4; ++r) {
        long row = rowb + i * 16 + (ln >> 4) * 4 + r;
        float v = acc[i][j][r] + bv;
        if (ACT == 2) v = eluf(v);
        if (OMODE == 0) {
          outF[z * o_zs + row * ldo + col] = v;
        } else {
          u16 h = f2bf(v);
          outH[z * o_zs + row * ldo + col] = h;
          outL[z * o_zs + row * ldo + col] = f2bf(v - bf2f(h));
        }
      }
    }
  }
}

// ---------------- graph diffusion: G = elu(A_norm @ h + x) -> hi/lo bf16 ----------------
__global__ __launch_bounds__(256) void k_diffuse(
    const float* __restrict__ A_norm, const float* __restrict__ h,
    const float* __restrict__ x, u16* __restrict__ Gh, u16* __restrict__ Gl,
    int b0, int NB)
{
  int b = blockIdx.x, br = blockIdx.y, t = threadIdx.x;
  __shared__ float sAT[64 * 64];
  __shared__ float sH[64 * 64];
  const float* An = A_norm + br * 4096;
  for (int idx = t; idx < 4096; idx += 256)
    sAT[(idx & 63) * 64 + (idx >> 6)] = An[idx];
  const float* hb = h + ((long)br * NB + b) * (64 * 512);
  const float* xb = x + ((long)br * Bn + (b0 + b)) * (64 * 512);
  u16* Ghb = Gh + ((long)br * NB + b) * (64 * 512);
  u16* Glb = Gl + ((long)br * NB + b) * (64 * 512);
  int c4 = t & 15, rb = (t >> 4) * 4;
  for (int dc = 0; dc < 512; dc += 64) {
    __syncthreads();
    for (int idx = t * 4; idx < 4096; idx += 1024) {
      int r = idx >> 6, c = idx & 63;
      *(float4*)&sH[idx] = *(const float4*)&hb[(long)r * 512 + dc + c];
    }
    __syncthreads();
    float acc[4][4] = {};
    #pragma unroll 4
    for (int j = 0; j < 64; ++j) {
      float a0 = sAT[j * 64 + rb + 0], a1 = sAT[j * 64 + rb + 1];
      float a2 = sAT[j * 64 + rb + 2], a3 = sAT[j * 64 + rb + 3];
      float4 hv = *(const float4*)&sH[j * 64 + c4 * 4];
      acc[0][0] = fmaf(a0, hv.x, acc[0][0]); acc[0][1] = fmaf(a0, hv.y, acc[0][1]);
      acc[0][2] = fmaf(a0, hv.z, acc[0][2]); acc[0][3] = fmaf(a0, hv.w, acc[0][3]);
      acc[1][0] = fmaf(a1, hv.x, acc[1][0]); acc[1][1] = fmaf(a1, hv.y, acc[1][1]);
      acc[1][2] = fmaf(a1, hv.z, acc[1][2]); acc[1][3] = fmaf(a1, hv.w, acc[1][3]);
      acc[2][0] = fmaf(a2, hv.x, acc[2][0]); acc[2][1] = fmaf(a2, hv.y, acc[2][1]);
      acc[2][2] = fmaf(a2, hv.z, acc[2][2]); acc[2][3] = fmaf(a2, hv.w, acc[2][3]);
      acc[3][0] = fmaf(a3, hv.x, acc[3][0]); acc[3][1] = fmaf(a3, hv.y, acc[3][1]);
      acc[3][2] = fmaf(a3, hv.z, acc[3][2]); acc[3][3] = fmaf(a3, hv.w, acc[3][3]);
    }
    #pragma unroll
    for (int i = 0; i < 4; ++i) {
      float4 xv = *(const float4*)&xb[(long)(rb + i) * 512 + dc + c4 * 4];
      float v0 = eluf(acc[i][0] + xv.x);
      float v1 = eluf(acc[i][1] + xv.y);
      float v2 = eluf(acc[i][2] + xv.z);
      float v3 = eluf(acc[i][3] + xv.w);
      u16x4 hh, ll;
      hh.x = f2bf(v0); ll.x = f2bf(v0 - bf2f(hh.x));
      hh.y = f2bf(v1); ll.y = f2bf(v1 - bf2f(hh.y));
      hh.z = f2bf(v2); ll.z = f2bf(v2 - bf2f(hh.z));
      hh.w = f2bf(v3); ll.w = f2bf(v3 - bf2f(hh.w));
      long o = (long)(rb + i) * 512 + dc + c4 * 4;
      *(u16x4*)&Ghb[o] = hh;
      *(u16x4*)&Glb[o] = ll;
    }
  }
}

// ---------------- attention + A_dyn apply, per (batch,branch) ----------------
// qkv layout: (3, NB*64, 256): cols 0-63 Q, 64-127 K, 128-191 V
__global__ __launch_bounds__(256) void k_attn(
    const float* __restrict__ qkv, const float* __restrict__ A_dyn,
    float* __restrict__ Zl, int b0, int NB)
{
  int b = blockIdx.x, br = blockIdx.y, t = threadIdx.x;
  __shared__ float sQ[64 * 65];
  __shared__ float sK[64 * 65];
  __shared__ float sS[64 * 65];
  const float* Qb = qkv + ((long)br * NB + b) * (64 * 256);
  for (int idx = t * 4; idx < 4096; idx += 1024) {
    int r = idx >> 6, c = idx & 63;
    float4 q4 = *(const float4*)&Qb[(long)r * 256 + c];
    float4 k4 = *(const float4*)&Qb[(long)r * 256 + 64 + c];
    sQ[r * 65 + c + 0] = q4.x; sQ[r * 65 + c + 1] = q4.y;
    sQ[r * 65 + c + 2] = q4.z; sQ[r * 65 + c + 3] = q4.w;
    sK[r * 65 + c + 0] = k4.x; sK[r * 65 + c + 1] = k4.y;
    sK[r * 65 + c + 2] = k4.z; sK[r * 65 + c + 3] = k4.w;
  }
  __syncthreads();
  int c4 = t & 15, rb = (t >> 4) * 4;
  float acc[4][4] = {};
  #pragma unroll 4
  for (int k = 0; k < 64; ++k) {
    float a0 = sQ[(rb + 0) * 65 + k], a1 = sQ[(rb + 1) * 65 + k];
    float a2 = sQ[(rb + 2) * 65 + k], a3 = sQ[(rb + 3) * 65 + k];
    #pragma unroll
    for (int q = 0; q < 4; ++q) {
      float bq = sK[(c4 * 4 + q) * 65 + k];
      acc[0][q] = fmaf(a0, bq, acc[0][q]); acc[1][q] = fmaf(a1, bq, acc[1][q]);
      acc[2][q] = fmaf(a2, bq, acc[2][q]); acc[3][q] = fmaf(a3, bq, acc[3][q]);
    }
  }
  #pragma unroll
  for (int i = 0; i < 4; ++i)
    #pragma unroll
    for (int q = 0; q < 4; ++q)
      sS[(rb + i) * 65 + c4 * 4 + q] = acc[i][q] * 0.125f;
  __syncthreads();
  {
    int r = t >> 2, l = t & 3;
    float m = -3.4e38f;
    #pragma unroll
    for (int c = 0; c < 16; ++c) m = fmaxf(m, sS[r * 65 + l * 16 + c]);
    m = fmaxf(m, __shfl_xor(m, 1));
    m = fmaxf(m, __shfl_xor(m, 2));
    float s = 0.f, e[16];
    #pragma unroll
    for (int c = 0; c < 16; ++c) { e[c] = expf(sS[r * 65 + l * 16 + c] - m); s += e[c]; }
    s += __shfl_xor(s, 1);
    s += __shfl_xor(s, 2);
    float inv = 1.f / s;
    #pragma unroll
    for (int c = 0; c < 16; ++c) sS[r * 65 + l * 16 + c] = e[c] * inv;
  }
  __syncthreads();
  for (int idx = t * 4; idx < 4096; idx += 1024) {
    int r = idx >> 6, c = idx & 63;
    float4 v4 = *(const float4*)&Qb[(long)r * 256 + 128 + c];
    sQ[r * 65 + c + 0] = v4.x; sQ[r * 65 + c + 1] = v4.y;
    sQ[r * 65 + c + 2] = v4.z; sQ[r * 65 + c + 3] = v4.w;
  }
  __syncthreads();
  float pv[4][4] = {};
  #pragma unroll 4
  for (int j = 0; j < 64; ++j) {
    float p0 = sS[(rb + 0) * 65 + j], p1 = sS[(rb + 1) * 65 + j];
    float p2 = sS[(rb + 2) * 65 + j], p3 = sS[(rb + 3) * 65 + j];
    #pragma unroll
    for (int q = 0; q < 4; ++q) {
      float vq = sQ[j * 65 + c4 * 4 + q];
      pv[0][q] = fmaf(p0, vq, pv[0][q]); pv[1][q] = fmaf(p1, vq, pv[1][q]);
      pv[2][q] = fmaf(p2, vq, pv[2][q]); pv[3][q] = fmaf(p3, vq, pv[3][q]);
    }
  }
  #pragma unroll
  for (int i = 0; i < 4; ++i)
    #pragma unroll
    for (int q = 0; q < 4; ++q)
      sK[(rb + i) * 65 + c4 * 4 + q] = pv[i][q];
  __syncthreads();
  const float* Ad = A_dyn + br * 4096;
  for (int idx = t; idx < 4096; idx += 256)
    sS[(idx >> 6) * 65 + (idx & 63)] = Ad[idx];
  __syncthreads();
  float zz[4][4] = {};
  #pragma unroll 4
  for (int j = 0; j < 64; ++j) {
    float a0 = sS[(rb + 0) * 65 + j], a1 = sS[(rb + 1) * 65 + j];
    float a2 = sS[(rb + 2) * 65 + j], a3 = sS[(rb + 3) * 65 + j];
    #pragma unroll
    for (int q = 0; q < 4; ++q) {
      float p = sK[j * 65 + c4 * 4 + q];
      zz[0][q] = fmaf(a0, p, zz[0][q]); zz[1][q] = fmaf(a1, p, zz[1][q]);
      zz[2][q] = fmaf(a2, p, zz[2][q]); zz[3][q] = fmaf(a3, p, zz[3][q]);
    }
  }
  long zbase = ((long)(b0 + b) * 64) * 192 + br * 64;
  #pragma unroll
  for (int i = 0; i < 4; ++i) {
    float4 o; o.x = zz[i][0]; o.y = zz[i][1]; o.z = zz[i][2]; o.w = zz[i][3];
    *(float4*)&Zl[zbase + (long)(rb + i) * 192 + c4 * 4] = o;
  }
}

// ---------------- generic f32 GEMM (fusion MLPs + head) ----------------
template<int ACT, bool RES, bool SPLITK>
__global__ __launch_bounds__(256) void k_gemm(
    int M, int N, int K,
    const float* __restrict__ A, long a_zs, int lda,
    const float* __restrict__ W, long w_zs,
    const float* __restrict__ bias, long b_zs,
    float* __restrict__ out, long o_zs,
    const float* __restrict__ resid, int k_chunk)
{
  int z  = blockIdx.z;
  int n0 = blockIdx.x * 64, m0 = blockIdx.y * 64;
  const float* Ab = A + (SPLITK ? 0 : z * a_zs);
  const float* Wb = W + (SPLITK ? 0 : z * w_zs);
  float* ob = out + z * o_zs;
  const float* bb = bias ? bias + z * b_zs : nullptr;
  const float* rb_ = RES ? resid + z * o_zs : nullptr;
  int k0   = SPLITK ? z * k_chunk : 0;
  int kend = SPLITK ? k0 + k_chunk : K;

  __shared__ float As[16][68];
  __shared__ float Bs[16][68];
  float acc[4][4] = {};
  int t  = threadIdx.x;
  int tm = t & 15, tn = t >> 4;
  int ar = t >> 2, ak = (t & 3) * 4;
  int bk = t >> 4, bn = (t & 15) * 4;

  for (int kt = k0; kt < kend; kt += 16) {
    float4 av = *(const float4*)&Ab[(long)(m0 + ar) * lda + kt + ak];
    float4 bv = *(const float4*)&Wb[(long)(kt + bk) * N + n0 + bn];
    __syncthreads();
    As[ak + 0][ar] = av.x; As[ak + 1][ar] = av.y;
    As[ak + 2][ar] = av.z; As[ak + 3][ar] = av.w;
    *(float4*)&Bs[bk][bn] = bv;
    __syncthreads();
    #pragma unroll
    for (int k = 0; k < 16; ++k) {
      float4 a = *(const float4*)&As[k][tm * 4];
      float4 b = *(const float4*)&Bs[k][tn * 4];
      acc[0][0] = fmaf(a.x, b.x, acc[0][0]); acc[0][1] = fmaf(a.x, b.y, acc[0][1]);
      acc[0][2] = fmaf(a.x, b.z, acc[0][2]); acc[0][3] = fmaf(a.x, b.w, acc[0][3]);
      acc[1][0] = fmaf(a.y, b.x, acc[1][0]); acc[1][1] = fmaf(a.y, b.y, acc[1][1]);
      acc[1][2] = fmaf(a.y, b.z, acc[1][2]); acc[1][3] = fmaf(a.y, b.w, acc[1][3]);
      acc[2][0] = fmaf(a.z, b.x, acc[2][0]); acc[2][1] = fmaf(a.z, b.y, acc[2][1]);
      acc[2][2] = fmaf(a.z, b.z, acc[2][2]); acc[2][3] = fmaf(a.z, b.w, acc[2][3]);
      acc[3][0] = fmaf(a.w, b.x, acc[3][0]); acc[3][1] = fmaf(a.w, b.y, acc[3][1]);
      acc[3][2] = fmaf(a.w, b.z, acc[3][2]); acc[3][3] = fmaf(a.w, b.w, acc[3][3]);
    }
  }

  #pragma unroll
  for (int i = 0; i < 4; ++i) {
    long row = m0 + tm * 4 + i;
    int  col = n0 + tn * 4;
    float v[4];
    #pragma unroll
    for (int j = 0; j < 4; ++j) {
      float x = acc[i][j] + (bb ? bb[col + j] : 0.f);
      if (ACT == 1) x = fmaxf(x, 0.f);
      if (ACT == 2) x = eluf(x);
      v[j] = x;
    }
    if (RES) {
      float4 r = *(const float4*)&rb_[row * N + col];
      v[0] += r.x; v[1] += r.y; v[2] += r.z; v[3] += r.w;
    }
    float4 o; o.x = v[0]; o.y = v[1]; o.z = v[2]; o.w = v[3];
    *(float4*)&ob[row * N + col] = o;
  }
}

// ---------------- fusion: Z_global, cw softmax, Zg, LayerNorm ----------------
__global__ __launch_bounds__(256) void k_fuse(
    const float* __restrict__ Zl, const float* __restrict__ A_init,
    const float* __restrict__ ln_g, const float* __restrict__ ln_b,
    float* __restrict__ Zg_out, float* __restrict__ Zln_out)
{
  int b = blockIdx.x, t = threadIdx.x;
  __shared__ float sZ[64 * 192];
  __shared__ float sAT[64 * 64];
  const float* Zb = Zl + (long)b * 64 * 192;
  for (int idx = t * 4; idx < 12288; idx += 1024)
    *(float4*)&sZ[idx] = *(const float4*)&Zb[idx];
  __syncthreads();
  if (t < 192) {
    float s = 0.f;
    #pragma unroll 8
    for (int j = 0; j < 64; ++j) s += sZ[j * 192 + t];
    sAT[t] = s * (1.f / 64.f);
  }
  __syncthreads();
  float m = -3.4e38f;
  for (int d = 0; d < 192; ++d) m = fmaxf(m, sAT[d]);
  float ssum = 0.f;
  for (int d = 0; d < 192; ++d) ssum += expf(sAT[d] - m);
  float cinv = 1.f / ssum;
  int c4 = t & 15, rb = (t >> 4) * 4;
  float cw[12];
  #pragma unroll
  for (int cc = 0; cc < 3; ++cc)
    #pragma unroll
    for (int q = 0; q < 4; ++q)
      cw[cc * 4 + q] = expf(sAT[cc * 64 + c4 * 4 + q] - m) * cinv;
  __syncthreads();
  for (int idx = t; idx < 4096; idx += 256)
    sAT[(idx & 63) * 64 + (idx >> 6)] = A_init[idx];
  __syncthreads();
  float acc[3][4][4] = {};
  for (int j = 0; j < 64; ++j) {
    float a0 = sAT[j * 64 + rb + 0], a1 = sAT[j * 64 + rb + 1];
    float a2 = sAT[j * 64 + rb + 2], a3 = sAT[j * 64 + rb + 3];
    #pragma unroll
    for (int cc = 0; cc < 3; ++cc) {
      float4 zv = *(const float4*)&sZ[j * 192 + cc * 64 + c4 * 4];
      acc[cc][0][0] = fmaf(a0, zv.x, acc[cc][0][0]); acc[cc][0][1] = fmaf(a0, zv.y, acc[cc][0][1]);
      acc[cc][0][2] = fmaf(a0, zv.z, acc[cc][0][2]); acc[cc][0][3] = fmaf(a0, zv.w, acc[cc][0][3]);
      acc[cc][1][0] = fmaf(a1, zv.x, acc[cc][1][0]); acc[cc][1][1] = fmaf(a1, zv.y, acc[cc][1][1]);
      acc[cc][1][2] = fmaf(a1, zv.z, acc[cc][1][2]); acc[cc][1][3] = fmaf(a1, zv.w, acc[cc][1][3]);
      acc[cc][2][0] = fmaf(a2, zv.x, acc[cc][2][0]); acc[cc][2][1] = fmaf(a2, zv.y, acc[cc][2][1]);
      acc[cc][2][2] = fmaf(a2, zv.z, acc[cc][2][2]); acc[cc][2][3] = fmaf(a2, zv.w, acc[cc][2][3]);
      acc[cc][3][0] = fmaf(a3, zv.x, acc[cc][3][0]); acc[cc][3][1] = fmaf(a3, zv.y, acc[cc][3][1]);
      acc[cc][3][2] = fmaf(a3, zv.z, acc[cc][3][2]); acc[cc][3][3] = fmaf(a3, zv.w, acc[cc][3][3]);
    }
  }
  long obase = (long)b * 64 * 192;
  #pragma unroll
  for (int cc = 0; cc < 3; ++cc)
    #pragma unroll
    for (int i = 0; i < 4; ++i)
      #pragma unroll
      for (int q = 0; q < 4; ++q)
        acc[cc][i][q] *= cw[cc * 4 + q];
  #pragma unroll
  for (int cc = 0; cc < 3; ++cc)
    #pragma unroll
    for (int i = 0; i < 4; ++i) {
      float4 o; o.x = acc[cc][i][0]; o.y = acc[cc][i][1]; o.z = acc[cc][i][2]; o.w = acc[cc][i][3];
      *(float4*)&Zg_out[obase + (long)(rb + i) * 192 + cc * 64 + c4 * 4] = o;
    }
  __syncthreads();
  #pragma unroll
  for (int cc = 0; cc < 3; ++cc)
    #pragma unroll
    for (int i = 0; i < 4; ++i) {
      float4 o; o.x = acc[cc][i][0]; o.y = acc[cc][i][1]; o.z = acc[cc][i][2]; o.w = acc[cc][i][3];
      *(float4*)&sZ[(rb + i) * 192 + cc * 64 + c4 * 4] = o;
    }
  __syncthreads();
  {
    int r = t >> 2, l = t & 3;
    float s = 0.f, s2 = 0.f;
    for (int ci = 0; ci < 48; ++ci) {
      int c = ci + r; if (c >= 48) c -= 48;
      float v = sZ[r * 192 + l * 48 + c];
      s += v; s2 = fmaf(v, v, s2);
    }
    s  += __shfl_xor(s, 1);  s  += __shfl_xor(s, 2);
    s2 += __shfl_xor(s2, 1); s2 += __shfl_xor(s2, 2);
    float mu = s * (1.f / 192.f);
    float var = s2 * (1.f / 192.f) - mu * mu;
    float rstd = rsqrtf(var + 1e-5f);
    for (int ci = 0; ci < 48; ++ci) {
      int c = ci + r; if (c >= 48) c -= 48;
      int d = l * 48 + c;
      float v = sZ[r * 192 + d];
      Zln_out[obase + (long)r * 192 + d] = (v - mu) * rstd * ln_g[d] + ln_b[d];
    }
  }
}

// ---------------- output head finalize ----------------
__global__ __launch_bounds__(128) void k_final(
    const float* __restrict__ partial, const float* __restrict__ o1b,
    const float* __restrict__ o2w, const float* __restrict__ o2b,
    float* __restrict__ logits, int nsplit)
{
  int b = blockIdx.x, t = threadIdx.x;
  __shared__ float sH[128];
  float a = o1b[t];
  for (int s = 0; s < nsplit; ++s) a += partial[(long)s * 512 * 128 + b * 128 + t];
  a = fmaxf(a, 0.f);
  sH[t] = a;
  __syncthreads();
  if (t < 2) {
    float z = o2b[t];
    #pragma unroll 8
    for (int h = 0; h < 128; ++h) z = fmaf(sH[h], o2w[h * 2 + t], z);
    logits[b * 2 + t] = z;
  }
}

extern "C" void kernel_launch(void* const* d_in, const int* in_sizes, int n_in,
                              void* d_out, int out_size, void* d_ws, size_t ws_size,
                              hipStream_t stream)
{
  const float* x      = (const float*)d_in[0];
  const float* A_init = (const float*)d_in[1];
  const float* f1w = (const float*)d_in[2];
  const float* f1b = (const float*)d_in[3];
  const float* f2w = (const float*)d_in[4];
  const float* f2b = (const float*)d_in[5];
  const float* q1w = (const float*)d_in[6];
  const float* q1b = (const float*)d_in[7];
  const float* q2w = (const float*)d_in[8];
  const float* q2b = (const float*)d_in[9];
  const float* wqw = (const float*)d_in[10];
  const float* wqb = (const float*)d_in[11];
  const float* wkw = (const float*)d_in[12];
  const float* wkb = (const float*)d_in[13];
  const float* wvw = (const float*)d_in[14];
  const float* wvb = (const float*)d_in[15];
  const float* lng = (const float*)d_in[16];
  const float* lnb = (const float*)d_in[17];
  const float* fc1w = (const float*)d_in[18];
  const float* fc1b = (const float*)d_in[19];
  const float* fc2w = (const float*)d_in[20];
  const float* fc2b = (const float*)d_in[21];
  const float* fm1w = (const float*)d_in[22];
  const float* fm1b = (const float*)d_in[23];
  const float* fm2w = (const float*)d_in[24];
  const float* fm2b = (const float*)d_in[25];
  const float* o1w  = (const float*)d_in[26];
  const float* o1b  = (const float*)d_in[27];
  const float* o2w  = (const float*)d_in[28];
  const float* o2b  = (const float*)d_in[29];

  float* outF   = (float*)d_out;
  float* logits = outF;                 // 512*2
  float* Zfused = outF + 1024;          // 512*64*192

  // ---- workspace layout (byte-based, 256B aligned) ----
  size_t off = 0;
  char* base = (char*)d_ws;
  auto alloc = [&](size_t bytes) -> void* {
    void* p = base + off;
    off += (bytes + 255) & ~(size_t)255;
    return p;
  };
  float* A_dyn  = (float*)alloc(3 * 4096 * 4);
  float* A_norm = (float*)alloc(3 * 4096 * 4);
  float* pmid   = (float*)alloc(3 * 32 * 256 * 4);
  float* mid    = (float*)alloc(3 * 256 * 4);
  u16* q1T_h = (u16*)alloc((size_t)3 * 512 * 512 * 2);
  u16* q1T_l = (u16*)alloc((size_t)3 * 512 * 512 * 2);
  u16* q2T_h = (u16*)alloc((size_t)3 * 512 * 512 * 2);
  u16* q2T_l = (u16*)alloc((size_t)3 * 512 * 512 * 2);
  u16* qkvT_h = (u16*)alloc((size_t)3 * 256 * 512 * 2);
  u16* qkvT_l = (u16*)alloc((size_t)3 * 256 * 512 * 2);
  float* qkvb = (float*)alloc(3 * 256 * 4);
  float* Zl = (float*)alloc(NZv * 4);
  float* s1 = (float*)alloc(NZv * 4);
  float* s2 = (float*)alloc(NZv * 4);
  float* s3 = (float*)alloc(NZv * 4);
  float* partial = (float*)alloc((size_t)24 * 512 * 128 * 4);

  // chunk size: per NB batch -> xh/xl/th/tl (4 x 196608 B) + h (393216 B)
  int NB = 512;
  while (NB > 32) {
    size_t chunk = (size_t)NB * 1179648ULL;
    if (off + chunk + 8192 <= ws_size) break;
    NB >>= 1;
  }
  long CM  = (long)NB * 64;             // rows per chunk per branch
  long SBe = (long)3 * NB * 32768;      // elements per hi/lo array (3 branches)
  u16* xh = (u16*)alloc(SBe * 2);
  u16* xl = (u16*)alloc(SBe * 2);
  u16* th = (u16*)alloc(SBe * 2);
  u16* tl = (u16*)alloc(SBe * 2);
  float* hb = (float*)alloc(SBe * 4);   // h f32; reused as QKV f32 (needs half)
  u16* Gh = th;                          // reuse t_a after GEMM2
  u16* Gl = tl;
  float* qkvB = hb;                      // reuse h after diffuse

  // dynamic graph (parallel): ~15 us total instead of 540 us
  k_dg1<<<dim3(32, 3), 256, 0, stream>>>(A_init, f1w, pmid);
  k_dg2<<<dim3(3), 256, 0, stream>>>(pmid, f1b, mid);
  k_dg3<<<dim3(16, 3), 256, 0, stream>>>(mid, f2w, f2b, A_dyn, A_norm);
  // weight splits (tiled, coalesced)
  k_cvt_wT<<<dim3(16, 16, 3), 256, 0, stream>>>(q1w, q1T_h, q1T_l, 512, 512);
  k_cvt_wT<<<dim3(16, 16, 3), 256, 0, stream>>>(q2w, q2T_h, q2T_l, 512, 512);
  k_cvt_qkvT<<<dim3(16, 8, 3), 256, 0, stream>>>(wqw, wkw, wvw, qkvT_h, qkvT_l);
  k_cvt_qkvb<<<dim3(3), 256, 0, stream>>>(wqb, wkb, wvb, qkvb);

  for (int b0 = 0; b0 < Bn; b0 += NB) {
    const float* xc = x + (long)b0 * 64 * 512;
    long an = (long)NB * 32768;
    // split x chunk -> xh/xl
    k_cvt_x<<<dim3((unsigned)(an / 1024), 3), 256, 0, stream>>>(
        xc, BCD, xh, xl, an, an);
    // t_a = elu(x@q1w + b) -> th/tl (bf16 hi/lo)
    k_mgemm<2, 1><<<dim3(4, (unsigned)(CM / 128), 3), 256, 0, stream>>>(
        (int)CM, 512, 512, 512, xh, xl, an, q1T_h, q1T_l, (long)512 * 512,
        q1b, 512, nullptr, th, tl, an);
    // h = t_a@q2w + b -> hb (f32)
    k_mgemm<0, 0><<<dim3(4, (unsigned)(CM / 128), 3), 256, 0, stream>>>(
        (int)CM, 512, 512, 512, th, tl, an, q2T_h, q2T_l, (long)512 * 512,
        q2b, 512, hb, nullptr, nullptr, an);
    // G = elu(A_norm@h + x) -> Gh/Gl (reuses th/tl)
    k_diffuse<<<dim3(NB, 3), 256, 0, stream>>>(A_norm, hb, x, Gh, Gl, b0, NB);
    // QKV = G@Wqkv + b -> qkvB (f32, ld 256) (reuses hb)
    k_mgemm<0, 0><<<dim3(2, (unsigned)(CM / 128), 3), 256, 0, stream>>>(
        (int)CM, 256, 512, 256, Gh, Gl, an, qkvT_h, qkvT_l, (long)256 * 512,
        qkvb, 256, qkvB, nullptr, nullptr, CM * 256);
    // attention + A_dyn apply -> Zl
    k_attn<<<dim3(NB, 3), 256, 0, stream>>>(qkvB, A_dyn, Zl, b0, NB);
  }

  // fusion: Zg -> s1, Z_ln -> s2
  k_fuse<<<dim3(Bn), 256, 0, stream>>>(Zl, A_init, lng, lnb, s1, s2);
  k_gemm<1, false, false><<<dim3(3, 512, 1), 256, 0, stream>>>(
      MTOT, 192, 192, s2, 0, 192, fc1w, 0, fc1b, 0, s3, 0, nullptr, 0);
  k_gemm<0, false, false><<<dim3(3, 512, 1), 256, 0, stream>>>(
      MTOT, 192, 192, s3, 0, 192, fc2w, 0, fc2b, 0, s2, 0, nullptr, 0);
  k_gemm<2, false, false><<<dim3(3, 512, 1), 256, 0, stream>>>(
      MTOT, 192, 192, s1, 0, 192, fm1w, 0, fm1b, 0, s3, 0, nullptr, 0);
  k_gemm<0, true, false><<<dim3(3, 512, 1), 256, 0, stream>>>(
      MTOT, 192, 192, s3, 0, 192, fm2w, 0, fm2b, 0, Zfused, 0, s2, 0);
  k_gemm<0, false, true><<<dim3(2, 8, 24), 256, 0, stream>>>(
      512, 128, 12288, Zfused, 0, 12288, o1w, 0, nullptr, 0,
      partial, (long)512 * 128, nullptr, 512);
  k_final<<<dim3(512), 128, 0, stream>>>(partial, o1b, o2w, o2b, logits, 24);
}